// Round 1
// baseline (331.826 us; speedup 1.0000x reference)
//
#include <hip/hip_runtime.h>
#include <hip/hip_bf16.h>
#include <cstdint>

#define DEVINL __device__ __forceinline__

typedef __attribute__((ext_vector_type(8))) short short8;   // 8 bf16 in 4 VGPRs
typedef __attribute__((ext_vector_type(4))) float f32x4;
typedef __attribute__((ext_vector_type(4))) unsigned short u16x4;

static constexpr int NB = 64, LL = 258, HH = 1024, QQ = 256;
static constexpr int WROWS = 33;          // max window length (2*16+1)
static constexpr int MU = 2176;           // 64*33 = 2112 padded to 17*128

// ---- workspace layout (bytes) ----
static constexpr size_t OFF_META = 0;                                  // int lstart[64], lcount[64]
static constexpr size_t SZ_WE   = (size_t)MU * HH * 2;                 // 4,456,448
static constexpr size_t OFF_WEHI = 1024;
static constexpr size_t OFF_WELO = OFF_WEHI + SZ_WE;
static constexpr size_t OFF_WAHI = OFF_WELO + SZ_WE;
static constexpr size_t OFF_WALO = OFF_WAHI + (size_t)HH * HH * 2;
static constexpr size_t OFF_WCBF = OFF_WALO + (size_t)HH * HH * 2;
static constexpr size_t OFF_HBF  = OFF_WCBF + (size_t)HH * 2 * HH * 2;
static constexpr size_t OFF_U    = OFF_HBF + (size_t)NB * QQ * HH * 2;
static constexpr size_t OFF_CTX  = OFF_U + (size_t)MU * HH * 4;
// total ~93.3 MB

DEVINL unsigned short f2bf(float x) {
    union { float f; uint32_t u; } v; v.f = x;
    uint32_t u = v.u;
    uint32_t r = (u + 0x7FFFu + ((u >> 16) & 1u)) >> 16;
    return (unsigned short)r;
}
DEVINL float bf2f(unsigned short b) {
    union { uint32_t u; float f; } v; v.u = ((uint32_t)b) << 16;
    return v.f;
}

template <typename T>
DEVINL void lds_load16(const T* g, T* l) {
    __builtin_amdgcn_global_load_lds(
        (const __attribute__((address_space(1))) void*)g,
        (__attribute__((address_space(3))) void*)l, 16, 0, 0);
}

// ---------------- K0: per-n window bounds ----------------
__global__ void k_window(const float* __restrict__ pt, const int* __restrict__ slen,
                         int* __restrict__ meta) {
    int n = threadIdx.x;
    if (n >= NB) return;
    float p = pt[n];
    float se = (float)slen[n];
    float s = fmaxf(p - 16.0f, 0.0f);
    float e = fminf(p + 16.0f, se);
    int ls = (int)ceilf(s);
    int le = (int)floorf(e); if (le > LL - 1) le = LL - 1;
    int lc = le - ls + 1;
    if (lc < 0) lc = 0;
    if (lc > WROWS) lc = WROWS;
    meta[n] = ls; meta[64 + n] = lc;
}

// ---------------- K1: f32 -> bf16 hi/lo split ----------------
__global__ __launch_bounds__(256) void k_split(const float* __restrict__ x,
                                               unsigned short* __restrict__ hi,
                                               unsigned short* __restrict__ lo, int count4) {
    int i = blockIdx.x * 256 + threadIdx.x;
    if (i >= count4) return;
    f32x4 v = ((const f32x4*)x)[i];
    u16x4 h, l;
#pragma unroll
    for (int j = 0; j < 4; ++j) {
        unsigned short hb = f2bf(v[j]);
        h[j] = hb;
        l[j] = f2bf(v[j] - bf2f(hb));
    }
    ((u16x4*)hi)[i] = h;
    ((u16x4*)lo)[i] = l;
}

// ---------------- K2: f32 -> bf16 (hi only) ----------------
__global__ __launch_bounds__(256) void k_tobf(const float* __restrict__ x,
                                              unsigned short* __restrict__ hi, int count4) {
    int i = blockIdx.x * 256 + threadIdx.x;
    if (i >= count4) return;
    f32x4 v = ((const f32x4*)x)[i];
    u16x4 h;
#pragma unroll
    for (int j = 0; j < 4; ++j) h[j] = f2bf(v[j]);
    ((u16x4*)hi)[i] = h;
}

// ---------------- K3: gather windowed enc rows -> bf16 hi/lo, zero-pad ----------------
__global__ __launch_bounds__(256) void k_gather(const float* __restrict__ enc,
                                                const int* __restrict__ meta,
                                                unsigned short* __restrict__ whi,
                                                unsigned short* __restrict__ wlo) {
    int r = blockIdx.x;       // 0..2175
    int t = threadIdx.x;      // 256 threads, 4 elems each
    const float* src = nullptr;
    bool valid = false;
    if (r < NB * WROWS) {
        int n = r / WROWS, li = r - n * WROWS;
        int ls = meta[n], lc = meta[64 + n];
        if (li < lc) { valid = true; src = enc + ((size_t)n * LL + ls + li) * HH; }
    }
    f32x4 v;
    if (valid) v = ((const f32x4*)src)[t];
    else { v[0] = 0.f; v[1] = 0.f; v[2] = 0.f; v[3] = 0.f; }
    u16x4 h, l;
#pragma unroll
    for (int j = 0; j < 4; ++j) {
        unsigned short hb = f2bf(v[j]);
        h[j] = hb;
        l[j] = f2bf(v[j] - bf2f(hb));
    }
    size_t o = (size_t)r * HH / 4 + t;
    ((u16x4*)whi)[o] = h;
    ((u16x4*)wlo)[o] = l;
}

// ---------------- K4: U = we @ W_a^T  (3-term split bf16 MFMA, fp32 out) ----------------
// A: we_{hi,lo} [2176][1024] bf16 row-major.  B^T = W_a_{hi,lo} [1024][1024] row-major.
__global__ __launch_bounds__(256) void k_ugemm(const unsigned short* __restrict__ Ahi,
                                               const unsigned short* __restrict__ Alo,
                                               const unsigned short* __restrict__ Bhi,
                                               const unsigned short* __restrict__ Blo,
                                               float* __restrict__ U) {
    constexpr int BK = 32;
    __shared__ unsigned short sAh[128 * BK], sAl[128 * BK], sBh[128 * BK], sBl[128 * BK];
    int tid = threadIdx.x;
    int w = tid >> 6, lane = tid & 63;
    int m0 = blockIdx.y * 128, n0 = blockIdx.x * 128;
    int wr = w >> 1, wc = w & 1;
    int srow = lane >> 2, slot = lane & 3;
    int r16 = lane & 15, khalf = lane >> 4;
    f32x4 acc[4][4] = {};

    for (int kb = 0; kb < 1024; kb += BK) {
        __syncthreads();   // previous compute done before overwrite
#pragma unroll
        for (int i = 0; i < 2; ++i) {
            int chunk = w * 2 + i;
            int trow = chunk * 16 + srow;
            int gcol = kb + slot * 8;
            size_t aoff = (size_t)(m0 + trow) * HH + gcol;
            size_t boff = (size_t)(n0 + trow) * HH + gcol;
            lds_load16(Ahi + aoff, &sAh[chunk * 512]);
            lds_load16(Alo + aoff, &sAl[chunk * 512]);
            lds_load16(Bhi + boff, &sBh[chunk * 512]);
            lds_load16(Blo + boff, &sBl[chunk * 512]);
        }
        asm volatile("s_waitcnt vmcnt(0)" ::: "memory");
        __syncthreads();

        short8 ah[4], al[4], bh[4], bl[4];
#pragma unroll
        for (int f = 0; f < 4; ++f) {
            int ai = (wr * 64 + f * 16 + r16) * BK + khalf * 8;
            ah[f] = *(const short8*)&sAh[ai];
            al[f] = *(const short8*)&sAl[ai];
            int bi = (wc * 64 + f * 16 + r16) * BK + khalf * 8;
            bh[f] = *(const short8*)&sBh[bi];
            bl[f] = *(const short8*)&sBl[bi];
        }
#pragma unroll
        for (int mf = 0; mf < 4; ++mf)
#pragma unroll
            for (int nf = 0; nf < 4; ++nf) {
                acc[mf][nf] = __builtin_amdgcn_mfma_f32_16x16x32_bf16(ah[mf], bh[nf], acc[mf][nf], 0, 0, 0);
                acc[mf][nf] = __builtin_amdgcn_mfma_f32_16x16x32_bf16(ah[mf], bl[nf], acc[mf][nf], 0, 0, 0);
                acc[mf][nf] = __builtin_amdgcn_mfma_f32_16x16x32_bf16(al[mf], bh[nf], acc[mf][nf], 0, 0, 0);
            }
    }
    int rg = lane >> 4;
#pragma unroll
    for (int mf = 0; mf < 4; ++mf)
#pragma unroll
        for (int nf = 0; nf < 4; ++nf)
#pragma unroll
            for (int r = 0; r < 4; ++r) {
                int m = m0 + wr * 64 + mf * 16 + rg * 4 + r;
                int nn = n0 + wc * 64 + nf * 16 + r16;
                U[(size_t)m * HH + nn] = acc[mf][nf][r];
            }
}

// ---------------- K5: windowed score + softmax + gauss + context (fp32) ----------------
__global__ __launch_bounds__(256) void k_attn(const float* __restrict__ ht,
                                              const float* __restrict__ enc,
                                              const float* __restrict__ U,
                                              const float* __restrict__ pt,
                                              const int* __restrict__ meta,
                                              unsigned short* __restrict__ ctx) {
    __shared__ union {
        struct { float h[32 * 68]; float u[33 * 68]; } p1;
        float e[33 * 256];
    } sm;
    __shared__ float sc[32 * 36];

    int tid = threadIdx.x;
    int n = blockIdx.x >> 3, q0 = (blockIdx.x & 7) * 32;
    int ls = meta[n], lc = meta[64 + n];
    float p = pt[n];

    int q = tid >> 3, g = tid & 7;   // 32 q-rows x 8 li-groups
    float accv[5] = {0.f, 0.f, 0.f, 0.f, 0.f};

    // ---- phase 1: score[q][li] = sum_k h[q,k] * U[li,k] ----
    for (int kb = 0; kb < 1024; kb += 64) {
        __syncthreads();
        for (int i = tid; i < 512; i += 256) {      // h tile [32][64] (pad 68)
            int r = i >> 4, c = i & 15;
            *(f32x4*)&sm.p1.h[r * 68 + c * 4] =
                *(const f32x4*)&ht[((size_t)(n * QQ + q0 + r)) * HH + kb + c * 4];
        }
        for (int i = tid; i < 528; i += 256) {      // U tile [33][64] (pad 68)
            int r = i >> 4, c = i & 15;
            *(f32x4*)&sm.p1.u[r * 68 + c * 4] =
                *(const f32x4*)&U[((size_t)(n * WROWS + r)) * HH + kb + c * 4];
        }
        __syncthreads();
#pragma unroll 4
        for (int k4 = 0; k4 < 16; ++k4) {
            f32x4 hv = *(const f32x4*)&sm.p1.h[q * 68 + k4 * 4];
#pragma unroll
            for (int s = 0; s < 5; ++s) {
                int li = g + 8 * s;
                if (li < WROWS) {
                    f32x4 uv = *(const f32x4*)&sm.p1.u[li * 68 + k4 * 4];
                    accv[s] = fmaf(hv[0], uv[0], accv[s]);
                    accv[s] = fmaf(hv[1], uv[1], accv[s]);
                    accv[s] = fmaf(hv[2], uv[2], accv[s]);
                    accv[s] = fmaf(hv[3], uv[3], accv[s]);
                }
            }
        }
    }

    // ---- phase 2: masked softmax + gaussian, 8 threads per q-row ----
    float mx = -1e30f;
#pragma unroll
    for (int s = 0; s < 5; ++s) { int li = g + 8 * s; if (li < lc) mx = fmaxf(mx, accv[s]); }
    for (int off = 1; off < 8; off <<= 1) mx = fmaxf(mx, __shfl_xor(mx, off, 8));
    float sum = 0.f, ex[5];
#pragma unroll
    for (int s = 0; s < 5; ++s) {
        int li = g + 8 * s;
        float e = (li < lc) ? __expf(accv[s] - mx) : 0.f;
        ex[s] = e; sum += e;
    }
    for (int off = 1; off < 8; off <<= 1) sum += __shfl_xor(sum, off, 8);
    float inv = 1.0f / sum;
#pragma unroll
    for (int s = 0; s < 5; ++s) {
        int li = g + 8 * s;
        if (li < WROWS) {
            float d = (float)(ls + li) - p;
            float gs = __expf(-(d * d) * (1.0f / 128.0f));
            sc[q * 36 + li] = ex[s] * inv * gs;
        }
    }
    __syncthreads();

    // ---- phase 3: context = align @ enc_window, write bf16 ----
    int lane = tid & 63, w = tid >> 6;
    for (int hb = 0; hb < 1024; hb += 256) {
        for (int i = tid; i < 33 * 64; i += 256) {
            int r = i >> 6, c = i & 63;
            if (r < lc)
                *(f32x4*)&sm.e[r * 256 + c * 4] =
                    *(const f32x4*)&enc[((size_t)n * LL + ls + r) * HH + hb + c * 4];
        }
        __syncthreads();
        for (int qq = w * 8; qq < w * 8 + 8; ++qq) {
            float a0 = 0.f, a1 = 0.f, a2 = 0.f, a3 = 0.f;
            for (int li = 0; li < lc; ++li) {
                float s = sc[qq * 36 + li];
                a0 = fmaf(s, sm.e[li * 256 + lane], a0);
                a1 = fmaf(s, sm.e[li * 256 + 64 + lane], a1);
                a2 = fmaf(s, sm.e[li * 256 + 128 + lane], a2);
                a3 = fmaf(s, sm.e[li * 256 + 192 + lane], a3);
            }
            size_t ob = ((size_t)(n * QQ + q0 + qq)) * HH + hb;
            ctx[ob + lane]        = f2bf(a0);
            ctx[ob + 64 + lane]   = f2bf(a1);
            ctx[ob + 128 + lane]  = f2bf(a2);
            ctx[ob + 192 + lane]  = f2bf(a3);
        }
        __syncthreads();
    }
}

// ---------------- K6: out = tanh([ctx | h] @ W_c^T), bf16 MFMA, dbuf 2-phase ----------------
// A: ctx_bf / h_bf [16384][1024].  B^T = W_c bf16 [1024][2048] row-major.
__global__ __launch_bounds__(256) void k_out_gemm(const unsigned short* __restrict__ Actx,
                                                  const unsigned short* __restrict__ Ahf,
                                                  const unsigned short* __restrict__ Bt,
                                                  float* __restrict__ out) {
    constexpr int BK = 32;
    __shared__ unsigned short sA[2][128 * BK], sB[2][128 * BK];
    int tid = threadIdx.x;
    int w = tid >> 6, lane = tid & 63;
    int m0 = blockIdx.y * 128, n0 = blockIdx.x * 128;
    int wr = w >> 1, wc = w & 1;
    int srow = lane >> 2, slot = lane & 3;
    int r16 = lane & 15, khalf = lane >> 4;
    f32x4 acc[4][4] = {};

    auto stage = [&](int buf, int kb) {
#pragma unroll
        for (int i = 0; i < 2; ++i) {
            int chunk = w * 2 + i;
            int trow = chunk * 16 + srow;
            int gcol = kb + slot * 8;
            const unsigned short* asrc = (kb < 1024)
                ? (Actx + (size_t)(m0 + trow) * HH + gcol)
                : (Ahf + (size_t)(m0 + trow) * HH + (gcol - 1024));
            lds_load16(asrc, &sA[buf][chunk * 512]);
            lds_load16(Bt + (size_t)(n0 + trow) * (2 * HH) + gcol, &sB[buf][chunk * 512]);
        }
    };

    stage(0, 0);
    asm volatile("s_waitcnt vmcnt(0)" ::: "memory");
    __syncthreads();

    for (int t = 0; t < 64; ++t) {
        int buf = t & 1;
        if (t + 1 < 64) stage(buf ^ 1, (t + 1) * BK);
        short8 af[4], bfr[4];
#pragma unroll
        for (int f = 0; f < 4; ++f)
            af[f] = *(const short8*)&sA[buf][(wr * 64 + f * 16 + r16) * BK + khalf * 8];
#pragma unroll
        for (int f = 0; f < 4; ++f)
            bfr[f] = *(const short8*)&sB[buf][(wc * 64 + f * 16 + r16) * BK + khalf * 8];
#pragma unroll
        for (int mf = 0; mf < 4; ++mf)
#pragma unroll
            for (int nf = 0; nf < 4; ++nf)
                acc[mf][nf] = __builtin_amdgcn_mfma_f32_16x16x32_bf16(af[mf], bfr[nf], acc[mf][nf], 0, 0, 0);
        asm volatile("s_waitcnt vmcnt(0)" ::: "memory");
        __syncthreads();
    }

    int rg = lane >> 4;
#pragma unroll
    for (int mf = 0; mf < 4; ++mf)
#pragma unroll
        for (int nf = 0; nf < 4; ++nf)
#pragma unroll
            for (int r = 0; r < 4; ++r) {
                int m = m0 + wr * 64 + mf * 16 + rg * 4 + r;
                int nn = n0 + wc * 64 + nf * 16 + r16;
                out[(size_t)m * HH + nn] = tanhf(acc[mf][nf][r]);
            }
}

extern "C" void kernel_launch(void* const* d_in, const int* in_sizes, int n_in,
                              void* d_out, int out_size, void* d_ws, size_t ws_size,
                              hipStream_t stream) {
    const float* enc  = (const float*)d_in[0];   // [64][258][1024]
    const float* ht   = (const float*)d_in[1];   // [64][256][1024]
    const int*   slen = (const int*)d_in[2];     // [64]
    const float* pt   = (const float*)d_in[3];   // [64]
    const float* Wa   = (const float*)d_in[4];   // [1024][1024]
    const float* Wc   = (const float*)d_in[5];   // [1024][2048]
    float* out = (float*)d_out;                  // [64][256][1024] f32

    char* ws = (char*)d_ws;                      // needs ~93.3 MB
    int* meta = (int*)(ws + OFF_META);
    unsigned short* wehi = (unsigned short*)(ws + OFF_WEHI);
    unsigned short* welo = (unsigned short*)(ws + OFF_WELO);
    unsigned short* wahi = (unsigned short*)(ws + OFF_WAHI);
    unsigned short* walo = (unsigned short*)(ws + OFF_WALO);
    unsigned short* wcbf = (unsigned short*)(ws + OFF_WCBF);
    unsigned short* hbf  = (unsigned short*)(ws + OFF_HBF);
    float*          Uf   = (float*)(ws + OFF_U);
    unsigned short* ctx  = (unsigned short*)(ws + OFF_CTX);

    hipLaunchKernelGGL(k_window, dim3(1), dim3(64), 0, stream, pt, slen, meta);
    hipLaunchKernelGGL(k_split, dim3((HH * HH / 4) / 256), dim3(256), 0, stream,
                       Wa, wahi, walo, HH * HH / 4);
    hipLaunchKernelGGL(k_tobf, dim3((HH * 2 * HH / 4) / 256), dim3(256), 0, stream,
                       Wc, wcbf, HH * 2 * HH / 4);
    hipLaunchKernelGGL(k_tobf, dim3((NB * QQ * HH / 4) / 256), dim3(256), 0, stream,
                       ht, hbf, NB * QQ * HH / 4);
    hipLaunchKernelGGL(k_gather, dim3(MU), dim3(256), 0, stream, enc, meta, wehi, welo);
    hipLaunchKernelGGL(k_ugemm, dim3(HH / 128, MU / 128), dim3(256), 0, stream,
                       wehi, welo, wahi, walo, Uf);
    hipLaunchKernelGGL(k_attn, dim3(NB * 8), dim3(256), 0, stream, ht, enc, Uf, pt, meta, ctx);
    hipLaunchKernelGGL(k_out_gemm, dim3(HH / 128, NB * QQ / 128), dim3(256), 0, stream,
                       ctx, hbf, wcbf, out);
}

// Round 2
// 274.993 us; speedup vs baseline: 1.2067x; 1.2067x over previous
//
#include <hip/hip_runtime.h>
#include <hip/hip_bf16.h>
#include <cstdint>

#define DEVINL __device__ __forceinline__

typedef __attribute__((ext_vector_type(8))) short short8;   // 8 bf16 in 4 VGPRs
typedef __attribute__((ext_vector_type(4))) float f32x4;
typedef __attribute__((ext_vector_type(4))) unsigned short u16x4;

static constexpr int NB = 64, LL = 258, HH = 1024, QQ = 256;
static constexpr int WROWS = 33;          // max window length (2*16+1)
static constexpr int MU = 2176;           // 64*33 = 2112 padded to 17*128

// ---- workspace layout (bytes) ----
static constexpr size_t OFF_META = 0;                                  // int lstart[64], lcount[64]
static constexpr size_t SZ_WE   = (size_t)MU * HH * 2;                 // 4,456,448
static constexpr size_t OFF_WEHI = 1024;
static constexpr size_t OFF_WELO = OFF_WEHI + SZ_WE;
static constexpr size_t OFF_WAHI = OFF_WELO + SZ_WE;
static constexpr size_t OFF_WALO = OFF_WAHI + (size_t)HH * HH * 2;
static constexpr size_t OFF_WCBF = OFF_WALO + (size_t)HH * HH * 2;
static constexpr size_t OFF_HBF  = OFF_WCBF + (size_t)HH * 2 * HH * 2;
static constexpr size_t OFF_U    = OFF_HBF + (size_t)NB * QQ * HH * 2;
static constexpr size_t OFF_CTX  = OFF_U + (size_t)MU * HH * 4;
// total ~93.3 MB

DEVINL unsigned short f2bf(float x) {
    union { float f; uint32_t u; } v; v.f = x;
    uint32_t u = v.u;
    uint32_t r = (u + 0x7FFFu + ((u >> 16) & 1u)) >> 16;
    return (unsigned short)r;
}
DEVINL float bf2f(unsigned short b) {
    union { uint32_t u; float f; } v; v.u = ((uint32_t)b) << 16;
    return v.f;
}

template <typename T>
DEVINL void lds_load16(const T* g, T* l) {
    __builtin_amdgcn_global_load_lds(
        (const __attribute__((address_space(1))) void*)g,
        (__attribute__((address_space(3))) void*)l, 16, 0, 0);
}

DEVINL float fast_tanh(float x) {
    float e = __expf(2.0f * x);
    return 1.0f - 2.0f / (e + 1.0f);
}

// ---------------- K0: per-n window bounds ----------------
__global__ void k_window(const float* __restrict__ pt, const int* __restrict__ slen,
                         int* __restrict__ meta) {
    int n = threadIdx.x;
    if (n >= NB) return;
    float p = pt[n];
    float se = (float)slen[n];
    float s = fmaxf(p - 16.0f, 0.0f);
    float e = fminf(p + 16.0f, se);
    int ls = (int)ceilf(s);
    int le = (int)floorf(e); if (le > LL - 1) le = LL - 1;
    int lc = le - ls + 1;
    if (lc < 0) lc = 0;
    if (lc > WROWS) lc = WROWS;
    meta[n] = ls; meta[64 + n] = lc;
}

// ---------------- K1: f32 -> bf16 hi/lo split ----------------
__global__ __launch_bounds__(256) void k_split(const float* __restrict__ x,
                                               unsigned short* __restrict__ hi,
                                               unsigned short* __restrict__ lo, int count4) {
    int i = blockIdx.x * 256 + threadIdx.x;
    if (i >= count4) return;
    f32x4 v = ((const f32x4*)x)[i];
    u16x4 h, l;
#pragma unroll
    for (int j = 0; j < 4; ++j) {
        unsigned short hb = f2bf(v[j]);
        h[j] = hb;
        l[j] = f2bf(v[j] - bf2f(hb));
    }
    ((u16x4*)hi)[i] = h;
    ((u16x4*)lo)[i] = l;
}

// ---------------- K2: f32 -> bf16 (hi only) ----------------
__global__ __launch_bounds__(256) void k_tobf(const float* __restrict__ x,
                                              unsigned short* __restrict__ hi, int count4) {
    int i = blockIdx.x * 256 + threadIdx.x;
    if (i >= count4) return;
    f32x4 v = ((const f32x4*)x)[i];
    u16x4 h;
#pragma unroll
    for (int j = 0; j < 4; ++j) h[j] = f2bf(v[j]);
    ((u16x4*)hi)[i] = h;
}

// ---------------- K3: gather windowed enc rows -> bf16 hi/lo, zero-pad ----------------
__global__ __launch_bounds__(256) void k_gather(const float* __restrict__ enc,
                                                const int* __restrict__ meta,
                                                unsigned short* __restrict__ whi,
                                                unsigned short* __restrict__ wlo) {
    int r = blockIdx.x;       // 0..2175
    int t = threadIdx.x;      // 256 threads, 4 elems each
    const float* src = nullptr;
    bool valid = false;
    if (r < NB * WROWS) {
        int n = r / WROWS, li = r - n * WROWS;
        int ls = meta[n], lc = meta[64 + n];
        if (li < lc) { valid = true; src = enc + ((size_t)n * LL + ls + li) * HH; }
    }
    f32x4 v;
    if (valid) v = ((const f32x4*)src)[t];
    else { v[0] = 0.f; v[1] = 0.f; v[2] = 0.f; v[3] = 0.f; }
    u16x4 h, l;
#pragma unroll
    for (int j = 0; j < 4; ++j) {
        unsigned short hb = f2bf(v[j]);
        h[j] = hb;
        l[j] = f2bf(v[j] - bf2f(hb));
    }
    size_t o = (size_t)r * HH / 4 + t;
    ((u16x4*)whi)[o] = h;
    ((u16x4*)wlo)[o] = l;
}

// ---------------- K4: U = we @ W_a^T  (3-term split bf16 MFMA, fp32 out) ----------------
// A: we_{hi,lo} [2176][1024] bf16 row-major.  B^T = W_a_{hi,lo} [1024][1024] row-major.
__global__ __launch_bounds__(256) void k_ugemm(const unsigned short* __restrict__ Ahi,
                                               const unsigned short* __restrict__ Alo,
                                               const unsigned short* __restrict__ Bhi,
                                               const unsigned short* __restrict__ Blo,
                                               float* __restrict__ U) {
    constexpr int BK = 32;
    __shared__ unsigned short sAh[128 * BK], sAl[128 * BK], sBh[128 * BK], sBl[128 * BK];
    int tid = threadIdx.x;
    int w = tid >> 6, lane = tid & 63;
    int m0 = blockIdx.y * 128, n0 = blockIdx.x * 128;
    int wr = w >> 1, wc = w & 1;
    int srow = lane >> 2, slot = lane & 3;
    int r16 = lane & 15, khalf = lane >> 4;
    f32x4 acc[4][4] = {};

    for (int kb = 0; kb < 1024; kb += BK) {
        __syncthreads();   // previous compute done before overwrite
#pragma unroll
        for (int i = 0; i < 2; ++i) {
            int chunk = w * 2 + i;
            int trow = chunk * 16 + srow;
            int gcol = kb + slot * 8;
            size_t aoff = (size_t)(m0 + trow) * HH + gcol;
            size_t boff = (size_t)(n0 + trow) * HH + gcol;
            lds_load16(Ahi + aoff, &sAh[chunk * 512]);
            lds_load16(Alo + aoff, &sAl[chunk * 512]);
            lds_load16(Bhi + boff, &sBh[chunk * 512]);
            lds_load16(Blo + boff, &sBl[chunk * 512]);
        }
        asm volatile("s_waitcnt vmcnt(0)" ::: "memory");
        __syncthreads();

        short8 ah[4], al[4], bh[4], bl[4];
#pragma unroll
        for (int f = 0; f < 4; ++f) {
            int ai = (wr * 64 + f * 16 + r16) * BK + khalf * 8;
            ah[f] = *(const short8*)&sAh[ai];
            al[f] = *(const short8*)&sAl[ai];
            int bi = (wc * 64 + f * 16 + r16) * BK + khalf * 8;
            bh[f] = *(const short8*)&sBh[bi];
            bl[f] = *(const short8*)&sBl[bi];
        }
#pragma unroll
        for (int mf = 0; mf < 4; ++mf)
#pragma unroll
            for (int nf = 0; nf < 4; ++nf) {
                acc[mf][nf] = __builtin_amdgcn_mfma_f32_16x16x32_bf16(ah[mf], bh[nf], acc[mf][nf], 0, 0, 0);
                acc[mf][nf] = __builtin_amdgcn_mfma_f32_16x16x32_bf16(ah[mf], bl[nf], acc[mf][nf], 0, 0, 0);
                acc[mf][nf] = __builtin_amdgcn_mfma_f32_16x16x32_bf16(al[mf], bh[nf], acc[mf][nf], 0, 0, 0);
            }
    }
    int rg = lane >> 4;
#pragma unroll
    for (int mf = 0; mf < 4; ++mf)
#pragma unroll
        for (int nf = 0; nf < 4; ++nf)
#pragma unroll
            for (int r = 0; r < 4; ++r) {
                int m = m0 + wr * 64 + mf * 16 + rg * 4 + r;
                int nn = n0 + wc * 64 + nf * 16 + r16;
                U[(size_t)m * HH + nn] = acc[mf][nf][r];
            }
}

// ---------------- K5: windowed score + softmax + gauss + context (fp32) ----------------
__global__ __launch_bounds__(256) void k_attn(const float* __restrict__ ht,
                                              const float* __restrict__ enc,
                                              const float* __restrict__ U,
                                              const float* __restrict__ pt,
                                              const int* __restrict__ meta,
                                              unsigned short* __restrict__ ctx) {
    __shared__ union {
        struct { float h[32 * 68]; float u[33 * 68]; } p1;
        float e[33 * 256];
    } sm;
    __shared__ float sc[32 * 36];

    int tid = threadIdx.x;
    int n = blockIdx.x >> 3, q0 = (blockIdx.x & 7) * 32;
    int ls = meta[n], lc = meta[64 + n];
    float p = pt[n];

    int q = tid >> 3, g = tid & 7;   // 32 q-rows x 8 li-groups
    float accv[5] = {0.f, 0.f, 0.f, 0.f, 0.f};

    // ---- phase 1: score[q][li] = sum_k h[q,k] * U[li,k] ----
    for (int kb = 0; kb < 1024; kb += 64) {
        __syncthreads();
        for (int i = tid; i < 512; i += 256) {      // h tile [32][64] (pad 68)
            int r = i >> 4, c = i & 15;
            *(f32x4*)&sm.p1.h[r * 68 + c * 4] =
                *(const f32x4*)&ht[((size_t)(n * QQ + q0 + r)) * HH + kb + c * 4];
        }
        for (int i = tid; i < 528; i += 256) {      // U tile [33][64] (pad 68)
            int r = i >> 4, c = i & 15;
            *(f32x4*)&sm.p1.u[r * 68 + c * 4] =
                *(const f32x4*)&U[((size_t)(n * WROWS + r)) * HH + kb + c * 4];
        }
        __syncthreads();
#pragma unroll 4
        for (int k4 = 0; k4 < 16; ++k4) {
            f32x4 hv = *(const f32x4*)&sm.p1.h[q * 68 + k4 * 4];
#pragma unroll
            for (int s = 0; s < 5; ++s) {
                int li = g + 8 * s;
                if (li < WROWS) {
                    f32x4 uv = *(const f32x4*)&sm.p1.u[li * 68 + k4 * 4];
                    accv[s] = fmaf(hv[0], uv[0], accv[s]);
                    accv[s] = fmaf(hv[1], uv[1], accv[s]);
                    accv[s] = fmaf(hv[2], uv[2], accv[s]);
                    accv[s] = fmaf(hv[3], uv[3], accv[s]);
                }
            }
        }
    }

    // ---- phase 2: masked softmax + gaussian, 8 threads per q-row ----
    float mx = -1e30f;
#pragma unroll
    for (int s = 0; s < 5; ++s) { int li = g + 8 * s; if (li < lc) mx = fmaxf(mx, accv[s]); }
    for (int off = 1; off < 8; off <<= 1) mx = fmaxf(mx, __shfl_xor(mx, off, 8));
    float sum = 0.f, ex[5];
#pragma unroll
    for (int s = 0; s < 5; ++s) {
        int li = g + 8 * s;
        float e = (li < lc) ? __expf(accv[s] - mx) : 0.f;
        ex[s] = e; sum += e;
    }
    for (int off = 1; off < 8; off <<= 1) sum += __shfl_xor(sum, off, 8);
    float inv = 1.0f / sum;
#pragma unroll
    for (int s = 0; s < 5; ++s) {
        int li = g + 8 * s;
        if (li < WROWS) {
            float d = (float)(ls + li) - p;
            float gs = __expf(-(d * d) * (1.0f / 128.0f));
            sc[q * 36 + li] = ex[s] * inv * gs;
        }
    }
    __syncthreads();

    // ---- phase 3: context = align @ enc_window, write bf16 ----
    int lane = tid & 63, w = tid >> 6;
    for (int hb = 0; hb < 1024; hb += 256) {
        for (int i = tid; i < 33 * 64; i += 256) {
            int r = i >> 6, c = i & 63;
            if (r < lc)
                *(f32x4*)&sm.e[r * 256 + c * 4] =
                    *(const f32x4*)&enc[((size_t)n * LL + ls + r) * HH + hb + c * 4];
        }
        __syncthreads();
        for (int qq = w * 8; qq < w * 8 + 8; ++qq) {
            float a0 = 0.f, a1 = 0.f, a2 = 0.f, a3 = 0.f;
            for (int li = 0; li < lc; ++li) {
                float s = sc[qq * 36 + li];
                a0 = fmaf(s, sm.e[li * 256 + lane], a0);
                a1 = fmaf(s, sm.e[li * 256 + 64 + lane], a1);
                a2 = fmaf(s, sm.e[li * 256 + 128 + lane], a2);
                a3 = fmaf(s, sm.e[li * 256 + 192 + lane], a3);
            }
            size_t ob = ((size_t)(n * QQ + q0 + qq)) * HH + hb;
            ctx[ob + lane]        = f2bf(a0);
            ctx[ob + 64 + lane]   = f2bf(a1);
            ctx[ob + 128 + lane]  = f2bf(a2);
            ctx[ob + 192 + lane]  = f2bf(a3);
        }
        __syncthreads();
    }
}

// ---------------- K6: out = tanh([ctx | h] @ W_c^T) ----------------
// 256x256 tile, BK=64, 8 waves, 128 KiB double-buffered LDS, 8-phase-style schedule.
// A = concat_K(ctx bf16 [16384][1024], hbf [16384][1024]); B^T = W_c bf16 [1024][2048].
// LDS swizzle (T2): linear global_load_lds dest + inverse-XOR on global source col +
// same XOR on ds_read slot (rule 21).  XCD swizzle (T1).  setprio around MFMA (T5).

#define RD_A(dst, buf, mh, mq, ksub) \
    dst = *(const short8*)&sA[(buf) * 16384 + (mh) * 8192 + \
        (wr * 64 + (mq) * 16 + r16) * 64 + ((((ksub) * 4 + kg) ^ (r16 & 7)) * 8)];
#define RD_B(dst, buf, nh, nq, ksub) \
    dst = *(const short8*)&sB[(buf) * 16384 + (nh) * 8192 + \
        (wc * 32 + (nq) * 16 + r16) * 64 + ((((ksub) * 4 + kg) ^ (r16 & 7)) * 8)];
#define MFMA_QUAD(MH, NH) \
    _Pragma("unroll") \
    for (int mq = 0; mq < 4; ++mq) { \
        _Pragma("unroll") \
        for (int nq = 0; nq < 2; ++nq) { \
            f32x4 c = acc[(MH) * 4 + mq][(NH) * 2 + nq]; \
            c = __builtin_amdgcn_mfma_f32_16x16x32_bf16(a[mq][0], b[nq][0], c, 0, 0, 0); \
            c = __builtin_amdgcn_mfma_f32_16x16x32_bf16(a[mq][1], b[nq][1], c, 0, 0, 0); \
            acc[(MH) * 4 + mq][(NH) * 2 + nq] = c; \
        } \
    }
#define PHASE_SYNC() \
    __builtin_amdgcn_s_barrier(); \
    asm volatile("s_waitcnt lgkmcnt(0)" ::: "memory"); \
    __builtin_amdgcn_sched_barrier(0);

__global__ __launch_bounds__(512, 1) void k_out_gemm256(
    const unsigned short* __restrict__ Actx,
    const unsigned short* __restrict__ Ahf,
    const unsigned short* __restrict__ Bt,
    float* __restrict__ out) {
    extern __shared__ unsigned short lds[];
    unsigned short* sA = lds;          // [2 buf][2 half][128*64]
    unsigned short* sB = lds + 32768;  // [2 buf][2 half][128*64]

    const int tid = threadIdx.x;
    const int wid = tid >> 6, lane = tid & 63;
    // T1: bijective XCD swizzle (nwg=256, 256%8==0): 32 consecutive tiles per XCD.
    const int bid = blockIdx.x;
    const int swz = (bid & 7) * 32 + (bid >> 3);
    const int mt = swz >> 2, ntile = swz & 3;     // N-tiles innermost: A-panel L2-resident
    const int m0 = mt * 256, n0 = ntile * 256;
    const int wr = wid >> 2, wc = wid & 3;
    const int r16 = lane & 15, kg = lane >> 4;

    const int srow = lane >> 3;                       // row-in-8-group for staging
    const int kswz = ((lane & 7) ^ srow) * 8;         // inverse-swizzled source col (elems)

    f32x4 acc[8][4] = {};

    auto stage_tile = [&](int buf, int kb) {
        const unsigned short* asrc = (kb < 1024) ? (Actx + kb) : (Ahf + (kb - 1024));
#pragma unroll
        for (int half = 0; half < 2; ++half)
#pragma unroll
            for (int i = 0; i < 2; ++i) {
                int r = half * 128 + i * 64 + wid * 8 + srow;
                lds_load16(asrc + (size_t)(m0 + r) * HH + kswz,
                           sA + buf * 16384 + half * 8192 + i * 4096 + wid * 512);
            }
#pragma unroll
        for (int half = 0; half < 2; ++half)
#pragma unroll
            for (int i = 0; i < 2; ++i) {
                int r = half * 128 + i * 64 + wid * 8 + srow;
                lds_load16(Bt + (size_t)(n0 + r) * (2 * HH) + kb + kswz,
                           sB + buf * 16384 + half * 8192 + i * 4096 + wid * 512);
            }
    };

    stage_tile(0, 0);
    asm volatile("s_waitcnt vmcnt(0)" ::: "memory");
    __builtin_amdgcn_s_barrier();

    short8 a[4][2], b[2][2];
    for (int t = 0; t < 32; ++t) {
        const int buf = t & 1;
        // ---- P1 (mh0, nh0): 12 ds_reads + full next-tile stage ----
#pragma unroll
        for (int mq = 0; mq < 4; ++mq) { RD_A(a[mq][0], buf, 0, mq, 0) RD_A(a[mq][1], buf, 0, mq, 1) }
#pragma unroll
        for (int nq = 0; nq < 2; ++nq) { RD_B(b[nq][0], buf, 0, nq, 0) RD_B(b[nq][1], buf, 0, nq, 1) }
        if (t + 1 < 32) stage_tile(buf ^ 1, (t + 1) * 64);
        PHASE_SYNC()
        __builtin_amdgcn_s_setprio(1);
        MFMA_QUAD(0, 0)
        __builtin_amdgcn_s_setprio(0);
        __builtin_amdgcn_s_barrier();
        // ---- P2 (mh0, nh1): 4 ds_reads (A kept) ----
#pragma unroll
        for (int nq = 0; nq < 2; ++nq) { RD_B(b[nq][0], buf, 1, nq, 0) RD_B(b[nq][1], buf, 1, nq, 1) }
        PHASE_SYNC()
        __builtin_amdgcn_s_setprio(1);
        MFMA_QUAD(0, 1)
        __builtin_amdgcn_s_setprio(0);
        __builtin_amdgcn_s_barrier();
        // ---- P3 (mh1, nh1): 8 ds_reads (B kept) ----
#pragma unroll
        for (int mq = 0; mq < 4; ++mq) { RD_A(a[mq][0], buf, 1, mq, 0) RD_A(a[mq][1], buf, 1, mq, 1) }
        PHASE_SYNC()
        __builtin_amdgcn_s_setprio(1);
        MFMA_QUAD(1, 1)
        __builtin_amdgcn_s_setprio(0);
        __builtin_amdgcn_s_barrier();
        // ---- P4 (mh1, nh0): 4 ds_reads (A kept); tile-end vmcnt+barrier ----
#pragma unroll
        for (int nq = 0; nq < 2; ++nq) { RD_B(b[nq][0], buf, 0, nq, 0) RD_B(b[nq][1], buf, 0, nq, 1) }
        PHASE_SYNC()
        __builtin_amdgcn_s_setprio(1);
        MFMA_QUAD(1, 0)
        __builtin_amdgcn_s_setprio(0);
        asm volatile("s_waitcnt vmcnt(0)" ::: "memory");
        __builtin_amdgcn_s_barrier();
    }

    // ---- epilogue: tanh + store ----
#pragma unroll
    for (int m = 0; m < 8; ++m)
#pragma unroll
        for (int n = 0; n < 4; ++n) {
            int row = m0 + (m >> 2) * 128 + wr * 64 + (m & 3) * 16 + kg * 4;
            int col = n0 + (n >> 1) * 128 + wc * 32 + (n & 1) * 16 + r16;
#pragma unroll
            for (int r = 0; r < 4; ++r)
                out[(size_t)(row + r) * HH + col] = fast_tanh(acc[m][n][r]);
        }
}

extern "C" void kernel_launch(void* const* d_in, const int* in_sizes, int n_in,
                              void* d_out, int out_size, void* d_ws, size_t ws_size,
                              hipStream_t stream) {
    const float* enc  = (const float*)d_in[0];   // [64][258][1024]
    const float* ht   = (const float*)d_in[1];   // [64][256][1024]
    const int*   slen = (const int*)d_in[2];     // [64]
    const float* pt   = (const float*)d_in[3];   // [64]
    const float* Wa   = (const float*)d_in[4];   // [1024][1024]
    const float* Wc   = (const float*)d_in[5];   // [1024][2048]
    float* out = (float*)d_out;                  // [64][256][1024] f32

    char* ws = (char*)d_ws;                      // needs ~93.3 MB
    int* meta = (int*)(ws + OFF_META);
    unsigned short* wehi = (unsigned short*)(ws + OFF_WEHI);
    unsigned short* welo = (unsigned short*)(ws + OFF_WELO);
    unsigned short* wahi = (unsigned short*)(ws + OFF_WAHI);
    unsigned short* walo = (unsigned short*)(ws + OFF_WALO);
    unsigned short* wcbf = (unsigned short*)(ws + OFF_WCBF);
    unsigned short* hbf  = (unsigned short*)(ws + OFF_HBF);
    float*          Uf   = (float*)(ws + OFF_U);
    unsigned short* ctx  = (unsigned short*)(ws + OFF_CTX);

    // allow 128 KiB dynamic LDS for the 256^2 GEMM (idempotent, capture-safe)
    hipFuncSetAttribute((const void*)k_out_gemm256,
                        hipFuncAttributeMaxDynamicSharedMemorySize, 131072);

    hipLaunchKernelGGL(k_window, dim3(1), dim3(64), 0, stream, pt, slen, meta);
    hipLaunchKernelGGL(k_split, dim3((HH * HH / 4) / 256), dim3(256), 0, stream,
                       Wa, wahi, walo, HH * HH / 4);
    hipLaunchKernelGGL(k_tobf, dim3((HH * 2 * HH / 4) / 256), dim3(256), 0, stream,
                       Wc, wcbf, HH * 2 * HH / 4);
    hipLaunchKernelGGL(k_tobf, dim3((NB * QQ * HH / 4) / 256), dim3(256), 0, stream,
                       ht, hbf, NB * QQ * HH / 4);
    hipLaunchKernelGGL(k_gather, dim3(MU), dim3(256), 0, stream, enc, meta, wehi, welo);
    hipLaunchKernelGGL(k_ugemm, dim3(HH / 128, MU / 128), dim3(256), 0, stream,
                       wehi, welo, wahi, walo, Uf);
    hipLaunchKernelGGL(k_attn, dim3(NB * 8), dim3(256), 0, stream, ht, enc, Uf, pt, meta, ctx);
    hipLaunchKernelGGL(k_out_gemm256, dim3(256), dim3(512), 131072, stream,
                       ctx, hbf, wcbf, out);
}

// Round 3
// 242.544 us; speedup vs baseline: 1.3681x; 1.1338x over previous
//
#include <hip/hip_runtime.h>
#include <hip/hip_bf16.h>
#include <cstdint>

#define DEVINL __device__ __forceinline__

typedef __attribute__((ext_vector_type(8))) short short8;   // 8 bf16 in 4 VGPRs
typedef __attribute__((ext_vector_type(4))) float f32x4;
typedef __attribute__((ext_vector_type(4))) unsigned short u16x4;

static constexpr int NB = 64, LL = 258, HH = 1024, QQ = 256;
static constexpr int WROWS = 33;          // max window length (2*16+1)
static constexpr int MU = 2176;           // 64*33 = 2112 padded to 17*128

// ---- workspace layout (bytes) ---- (identical footprint to round 1/2: ~93.3 MB)
static constexpr size_t OFF_META = 0;                                  // int lstart[64], lcount[64]
static constexpr size_t SZ_WE   = (size_t)MU * HH * 2;                 // 4,456,448
static constexpr size_t OFF_WEHI = 1024;
static constexpr size_t OFF_WELO = OFF_WEHI + SZ_WE;
static constexpr size_t OFF_WAHI = OFF_WELO + SZ_WE;
static constexpr size_t OFF_WALO = OFF_WAHI + (size_t)HH * HH * 2;
static constexpr size_t OFF_WCBF = OFF_WALO + (size_t)HH * HH * 2;
static constexpr size_t OFF_HBF  = OFF_WCBF + (size_t)HH * 2 * HH * 2;
static constexpr size_t OFF_U    = OFF_HBF + (size_t)NB * QQ * HH * 2; // now Uhi/Ulo bf16 (same 8.9MB slot)
static constexpr size_t OFF_UHI  = OFF_U;
static constexpr size_t OFF_ULO  = OFF_U + (size_t)MU * HH * 2;
static constexpr size_t OFF_CTX  = OFF_U + (size_t)MU * HH * 4;

DEVINL unsigned short f2bf(float x) {
    union { float f; uint32_t u; } v; v.f = x;
    uint32_t u = v.u;
    uint32_t r = (u + 0x7FFFu + ((u >> 16) & 1u)) >> 16;
    return (unsigned short)r;
}
DEVINL float bf2f(unsigned short b) {
    union { uint32_t u; float f; } v; v.u = ((uint32_t)b) << 16;
    return v.f;
}

template <typename T>
DEVINL void lds_load16(const T* g, T* l) {
    __builtin_amdgcn_global_load_lds(
        (const __attribute__((address_space(1))) void*)g,
        (__attribute__((address_space(3))) void*)l, 16, 0, 0);
}

DEVINL float fast_tanh(float x) {
    float e = __expf(2.0f * x);
    return 1.0f - 2.0f / (e + 1.0f);
}

// ---------------- K0: per-n window bounds ----------------
__global__ void k_window(const float* __restrict__ pt, const int* __restrict__ slen,
                         int* __restrict__ meta) {
    int n = threadIdx.x;
    if (n >= NB) return;
    float p = pt[n];
    float se = (float)slen[n];
    float s = fmaxf(p - 16.0f, 0.0f);
    float e = fminf(p + 16.0f, se);
    int ls = (int)ceilf(s);
    int le = (int)floorf(e); if (le > LL - 1) le = LL - 1;
    int lc = le - ls + 1;
    if (lc < 0) lc = 0;
    if (lc > WROWS) lc = WROWS;
    meta[n] = ls; meta[64 + n] = lc;
}

// ---------------- K1: f32 -> bf16 hi/lo split ----------------
__global__ __launch_bounds__(256) void k_split(const float* __restrict__ x,
                                               unsigned short* __restrict__ hi,
                                               unsigned short* __restrict__ lo, int count4) {
    int i = blockIdx.x * 256 + threadIdx.x;
    if (i >= count4) return;
    f32x4 v = ((const f32x4*)x)[i];
    u16x4 h, l;
#pragma unroll
    for (int j = 0; j < 4; ++j) {
        unsigned short hb = f2bf(v[j]);
        h[j] = hb;
        l[j] = f2bf(v[j] - bf2f(hb));
    }
    ((u16x4*)hi)[i] = h;
    ((u16x4*)lo)[i] = l;
}

// ---------------- K2: f32 -> bf16 (hi only) ----------------
__global__ __launch_bounds__(256) void k_tobf(const float* __restrict__ x,
                                              unsigned short* __restrict__ hi, int count4) {
    int i = blockIdx.x * 256 + threadIdx.x;
    if (i >= count4) return;
    f32x4 v = ((const f32x4*)x)[i];
    u16x4 h;
#pragma unroll
    for (int j = 0; j < 4; ++j) h[j] = f2bf(v[j]);
    ((u16x4*)hi)[i] = h;
}

// ---------------- K3: gather windowed enc rows -> bf16 hi/lo, zero-pad ----------------
__global__ __launch_bounds__(256) void k_gather(const float* __restrict__ enc,
                                                const int* __restrict__ meta,
                                                unsigned short* __restrict__ whi,
                                                unsigned short* __restrict__ wlo) {
    int r = blockIdx.x;       // 0..2175
    int t = threadIdx.x;      // 256 threads, 4 elems each
    const float* src = nullptr;
    bool valid = false;
    if (r < NB * WROWS) {
        int n = r / WROWS, li = r - n * WROWS;
        int ls = meta[n], lc = meta[64 + n];
        if (li < lc) { valid = true; src = enc + ((size_t)n * LL + ls + li) * HH; }
    }
    f32x4 v;
    if (valid) v = ((const f32x4*)src)[t];
    else { v[0] = 0.f; v[1] = 0.f; v[2] = 0.f; v[3] = 0.f; }
    u16x4 h, l;
#pragma unroll
    for (int j = 0; j < 4; ++j) {
        unsigned short hb = f2bf(v[j]);
        h[j] = hb;
        l[j] = f2bf(v[j] - bf2f(hb));
    }
    size_t o = (size_t)r * HH / 4 + t;
    ((u16x4*)whi)[o] = h;
    ((u16x4*)wlo)[o] = l;
}

// ---------------- K4: U = we @ W_a^T  (3-term split bf16 MFMA, bf16 hi/lo out) ----------------
__global__ __launch_bounds__(256) void k_ugemm(const unsigned short* __restrict__ Ahi,
                                               const unsigned short* __restrict__ Alo,
                                               const unsigned short* __restrict__ Bhi,
                                               const unsigned short* __restrict__ Blo,
                                               unsigned short* __restrict__ Uhi,
                                               unsigned short* __restrict__ Ulo) {
    constexpr int BK = 32;
    __shared__ unsigned short sAh[128 * BK], sAl[128 * BK], sBh[128 * BK], sBl[128 * BK];
    int tid = threadIdx.x;
    int w = tid >> 6, lane = tid & 63;
    int m0 = blockIdx.y * 128, n0 = blockIdx.x * 128;
    int wr = w >> 1, wc = w & 1;
    int srow = lane >> 2, slot = lane & 3;
    int r16 = lane & 15, khalf = lane >> 4;
    f32x4 acc[4][4] = {};

    for (int kb = 0; kb < 1024; kb += BK) {
        __syncthreads();
#pragma unroll
        for (int i = 0; i < 2; ++i) {
            int chunk = w * 2 + i;
            int trow = chunk * 16 + srow;
            int gcol = kb + slot * 8;
            size_t aoff = (size_t)(m0 + trow) * HH + gcol;
            size_t boff = (size_t)(n0 + trow) * HH + gcol;
            lds_load16(Ahi + aoff, &sAh[chunk * 512]);
            lds_load16(Alo + aoff, &sAl[chunk * 512]);
            lds_load16(Bhi + boff, &sBh[chunk * 512]);
            lds_load16(Blo + boff, &sBl[chunk * 512]);
        }
        asm volatile("s_waitcnt vmcnt(0)" ::: "memory");
        __syncthreads();

        short8 ah[4], al[4], bh[4], bl[4];
#pragma unroll
        for (int f = 0; f < 4; ++f) {
            int ai = (wr * 64 + f * 16 + r16) * BK + khalf * 8;
            ah[f] = *(const short8*)&sAh[ai];
            al[f] = *(const short8*)&sAl[ai];
            int bi = (wc * 64 + f * 16 + r16) * BK + khalf * 8;
            bh[f] = *(const short8*)&sBh[bi];
            bl[f] = *(const short8*)&sBl[bi];
        }
#pragma unroll
        for (int mf = 0; mf < 4; ++mf)
#pragma unroll
            for (int nf = 0; nf < 4; ++nf) {
                acc[mf][nf] = __builtin_amdgcn_mfma_f32_16x16x32_bf16(ah[mf], bh[nf], acc[mf][nf], 0, 0, 0);
                acc[mf][nf] = __builtin_amdgcn_mfma_f32_16x16x32_bf16(ah[mf], bl[nf], acc[mf][nf], 0, 0, 0);
                acc[mf][nf] = __builtin_amdgcn_mfma_f32_16x16x32_bf16(al[mf], bh[nf], acc[mf][nf], 0, 0, 0);
            }
    }
    int rg = lane >> 4;
#pragma unroll
    for (int mf = 0; mf < 4; ++mf)
#pragma unroll
        for (int nf = 0; nf < 4; ++nf)
#pragma unroll
            for (int r = 0; r < 4; ++r) {
                int m = m0 + wr * 64 + mf * 16 + rg * 4 + r;
                int nn = n0 + wc * 64 + nf * 16 + r16;
                float v = acc[mf][nf][r];
                unsigned short h = f2bf(v);
                Uhi[(size_t)m * HH + nn] = h;
                Ulo[(size_t)m * HH + nn] = f2bf(v - bf2f(h));
            }
}

// ---------------- K5: fused MFMA attention: score + softmax + gauss + PV ----------------
// One block per (n, 32-q slice). 4 waves.
// Phase A: score[32][48] = h[32][1024] @ Uw[48][1024]^T, 3-term hi/lo MFMA, K split over waves.
// Phase B: ctx[32][1024] = P[32][64] @ Ew[64][1024], 2-term P-split MFMA, E^T gathered from global.
__global__ __launch_bounds__(256) void k_attn_mfma(const float* __restrict__ ht,
                                                   const float* __restrict__ enc,
                                                   const unsigned short* __restrict__ Uhi,
                                                   const unsigned short* __restrict__ Ulo,
                                                   const float* __restrict__ pt,
                                                   const int* __restrict__ meta,
                                                   unsigned short* __restrict__ ctx) {
    __shared__ float sPart[4][32 * 48];          // 24.6 KB per-wave partial scores
    __shared__ float sScore[32 * 48];            // 6 KB reduced score -> P fp32
    __shared__ unsigned short sPhi[32 * 72];     // P hi, stride 72 u16 (144B: aligned, 2-way banks)
    __shared__ unsigned short sPlo[32 * 72];     // P lo

    const int tid = threadIdx.x;
    const int w = tid >> 6, lane = tid & 63;
    const int n = blockIdx.x >> 3, q0 = (blockIdx.x & 7) * 32;
    const int ls = meta[n], lc = meta[64 + n];
    const float p = pt[n];
    const int r16 = lane & 15, khalf = lane >> 4, rg = lane >> 4;

    const float* hbase = ht + ((size_t)(n * QQ + q0)) * HH;
    const unsigned short* uhbase = Uhi + (size_t)n * WROWS * HH;
    const unsigned short* ulbase = Ulo + (size_t)n * WROWS * HH;

    // ---- Phase A ----
    f32x4 acc[2][3] = {};
    for (int ks = 0; ks < 8; ++ks) {
        int kcol = w * 256 + ks * 32 + khalf * 8;
        short8 ah[2], al[2];
#pragma unroll
        for (int mf = 0; mf < 2; ++mf) {
            const float* src = hbase + (size_t)(mf * 16 + r16) * HH + kcol;
            f32x4 v0 = *(const f32x4*)src;
            f32x4 v1 = *(const f32x4*)(src + 4);
            float vv[8] = {v0[0], v0[1], v0[2], v0[3], v1[0], v1[1], v1[2], v1[3]};
#pragma unroll
            for (int j = 0; j < 8; ++j) {
                unsigned short hb = f2bf(vv[j]);
                ah[mf][j] = (short)hb;
                al[mf][j] = (short)f2bf(vv[j] - bf2f(hb));
            }
        }
#pragma unroll
        for (int nf = 0; nf < 3; ++nf) {
            size_t uoff = (size_t)(nf * 16 + r16) * HH + kcol;   // row may spill into next n's U: finite, masked later
            short8 bh = *(const short8*)(uhbase + uoff);
            short8 bl = *(const short8*)(ulbase + uoff);
#pragma unroll
            for (int mf = 0; mf < 2; ++mf) {
                acc[mf][nf] = __builtin_amdgcn_mfma_f32_16x16x32_bf16(ah[mf], bh, acc[mf][nf], 0, 0, 0);
                acc[mf][nf] = __builtin_amdgcn_mfma_f32_16x16x32_bf16(ah[mf], bl, acc[mf][nf], 0, 0, 0);
                acc[mf][nf] = __builtin_amdgcn_mfma_f32_16x16x32_bf16(al[mf], bh, acc[mf][nf], 0, 0, 0);
            }
        }
    }
    // write per-wave partials
#pragma unroll
    for (int mf = 0; mf < 2; ++mf)
#pragma unroll
        for (int nf = 0; nf < 3; ++nf)
#pragma unroll
            for (int r = 0; r < 4; ++r)
                sPart[w][(mf * 16 + rg * 4 + r) * 48 + nf * 16 + r16] = acc[mf][nf][r];
    __syncthreads();

    // ---- reduce + softmax + gauss ----
    {
        int q = tid >> 3, g = tid & 7;            // 32 rows x 8 threads
        float sc6[6];
#pragma unroll
        for (int s = 0; s < 6; ++s) {
            int li = g + 8 * s;
            int o = q * 48 + li;
            sc6[s] = sPart[0][o] + sPart[1][o] + sPart[2][o] + sPart[3][o];
        }
        float mx = -1e30f;
#pragma unroll
        for (int s = 0; s < 6; ++s) { int li = g + 8 * s; if (li < lc) mx = fmaxf(mx, sc6[s]); }
        for (int off = 1; off < 8; off <<= 1) mx = fmaxf(mx, __shfl_xor(mx, off, 8));
        float sum = 0.f, ex[6];
#pragma unroll
        for (int s = 0; s < 6; ++s) {
            int li = g + 8 * s;
            float e = (li < lc) ? __expf(sc6[s] - mx) : 0.f;
            ex[s] = e; sum += e;
        }
        for (int off = 1; off < 8; off <<= 1) sum += __shfl_xor(sum, off, 8);
        float inv = 1.0f / sum;
#pragma unroll
        for (int s = 0; s < 6; ++s) {
            int li = g + 8 * s;
            float d = (float)(ls + li) - p;
            float gs = __expf(-(d * d) * (1.0f / 128.0f));
            sScore[q * 48 + li] = ex[s] * inv * gs;
        }
    }
    __syncthreads();

    // ---- split P into hi/lo bf16 [32][64] (pad cols 48..63 = 0) ----
    {
        int row = tid >> 3, c0 = (tid & 7) * 8;
#pragma unroll
        for (int j = 0; j < 8; ++j) {
            int c = c0 + j;
            float pv = (c < 48) ? sScore[row * 48 + c] : 0.f;
            unsigned short hb = f2bf(pv);
            sPhi[row * 72 + c] = hb;
            sPlo[row * 72 + c] = f2bf(pv - bf2f(hb));
        }
    }
    __syncthreads();

    // ---- Phase B: ctx[32][1024] = P @ Ew.  Waves split N=1024 into 4x256. ----
    const float* ebase = enc + ((size_t)n * LL + ls) * HH;
    f32x4 accB[2][16] = {};
    const int hcol0 = w * 256;
#pragma unroll 2
    for (int nf = 0; nf < 16; ++nf) {
        int hc = hcol0 + nf * 16 + r16;
#pragma unroll
        for (int kstep = 0; kstep < 2; ++kstep) {
            short8 bfrag;
#pragma unroll
            for (int j = 0; j < 8; ++j) {
                int li = kstep * 32 + khalf * 8 + j;
                int lr = (li < lc) ? li : 0;      // clamp: stays in window, P=0 kills it
                bfrag[j] = (short)f2bf(ebase[(size_t)lr * HH + hc]);
            }
#pragma unroll
            for (int mf = 0; mf < 2; ++mf) {
                short8 pa = *(const short8*)&sPhi[(mf * 16 + r16) * 72 + kstep * 32 + khalf * 8];
                short8 pl = *(const short8*)&sPlo[(mf * 16 + r16) * 72 + kstep * 32 + khalf * 8];
                accB[mf][nf] = __builtin_amdgcn_mfma_f32_16x16x32_bf16(pa, bfrag, accB[mf][nf], 0, 0, 0);
                accB[mf][nf] = __builtin_amdgcn_mfma_f32_16x16x32_bf16(pl, bfrag, accB[mf][nf], 0, 0, 0);
            }
        }
    }
    // ---- store ctx bf16 ----
#pragma unroll
    for (int mf = 0; mf < 2; ++mf)
#pragma unroll
        for (int nf = 0; nf < 16; ++nf)
#pragma unroll
            for (int r = 0; r < 4; ++r)
                ctx[(size_t)(n * QQ + q0 + mf * 16 + rg * 4 + r) * HH + hcol0 + nf * 16 + r16] =
                    f2bf(accB[mf][nf][r]);
}

// ---------------- K6: out = tanh([ctx | h] @ W_c^T) ----------------
#define RD_A(dst, buf, mh, mq, ksub) \
    dst = *(const short8*)&sA[(buf) * 16384 + (mh) * 8192 + \
        (wr * 64 + (mq) * 16 + r16) * 64 + ((((ksub) * 4 + kg) ^ (r16 & 7)) * 8)];
#define RD_B(dst, buf, nh, nq, ksub) \
    dst = *(const short8*)&sB[(buf) * 16384 + (nh) * 8192 + \
        (wc * 32 + (nq) * 16 + r16) * 64 + ((((ksub) * 4 + kg) ^ (r16 & 7)) * 8)];
#define MFMA_QUAD(MH, NH) \
    _Pragma("unroll") \
    for (int mq = 0; mq < 4; ++mq) { \
        _Pragma("unroll") \
        for (int nq = 0; nq < 2; ++nq) { \
            f32x4 c = acc[(MH) * 4 + mq][(NH) * 2 + nq]; \
            c = __builtin_amdgcn_mfma_f32_16x16x32_bf16(a[mq][0], b[nq][0], c, 0, 0, 0); \
            c = __builtin_amdgcn_mfma_f32_16x16x32_bf16(a[mq][1], b[nq][1], c, 0, 0, 0); \
            acc[(MH) * 4 + mq][(NH) * 2 + nq] = c; \
        } \
    }
#define PHASE_SYNC() \
    __builtin_amdgcn_s_barrier(); \
    asm volatile("s_waitcnt lgkmcnt(0)" ::: "memory"); \
    __builtin_amdgcn_sched_barrier(0);

__global__ __launch_bounds__(512, 1) void k_out_gemm256(
    const unsigned short* __restrict__ Actx,
    const unsigned short* __restrict__ Ahf,
    const unsigned short* __restrict__ Bt,
    float* __restrict__ out) {
    extern __shared__ unsigned short lds[];
    unsigned short* sA = lds;          // [2 buf][2 half][128*64]
    unsigned short* sB = lds + 32768;  // [2 buf][2 half][128*64]

    const int tid = threadIdx.x;
    const int wid = tid >> 6, lane = tid & 63;
    const int bid = blockIdx.x;
    const int swz = (bid & 7) * 32 + (bid >> 3);
    const int mt = swz >> 2, ntile = swz & 3;
    const int m0 = mt * 256, n0 = ntile * 256;
    const int wr = wid >> 2, wc = wid & 3;
    const int r16 = lane & 15, kg = lane >> 4;

    const int srow = lane >> 3;
    const int kswz = ((lane & 7) ^ srow) * 8;

    f32x4 acc[8][4] = {};

    auto stage_tile = [&](int buf, int kb) {
        const unsigned short* asrc = (kb < 1024) ? (Actx + kb) : (Ahf + (kb - 1024));
#pragma unroll
        for (int half = 0; half < 2; ++half)
#pragma unroll
            for (int i = 0; i < 2; ++i) {
                int r = half * 128 + i * 64 + wid * 8 + srow;
                lds_load16(asrc + (size_t)(m0 + r) * HH + kswz,
                           sA + buf * 16384 + half * 8192 + i * 4096 + wid * 512);
            }
#pragma unroll
        for (int half = 0; half < 2; ++half)
#pragma unroll
            for (int i = 0; i < 2; ++i) {
                int r = half * 128 + i * 64 + wid * 8 + srow;
                lds_load16(Bt + (size_t)(n0 + r) * (2 * HH) + kb + kswz,
                           sB + buf * 16384 + half * 8192 + i * 4096 + wid * 512);
            }
    };

    stage_tile(0, 0);
    asm volatile("s_waitcnt vmcnt(0)" ::: "memory");
    __builtin_amdgcn_s_barrier();

    short8 a[4][2], b[2][2];
    for (int t = 0; t < 32; ++t) {
        const int buf = t & 1;
#pragma unroll
        for (int mq = 0; mq < 4; ++mq) { RD_A(a[mq][0], buf, 0, mq, 0) RD_A(a[mq][1], buf, 0, mq, 1) }
#pragma unroll
        for (int nq = 0; nq < 2; ++nq) { RD_B(b[nq][0], buf, 0, nq, 0) RD_B(b[nq][1], buf, 0, nq, 1) }
        if (t + 1 < 32) stage_tile(buf ^ 1, (t + 1) * 64);
        PHASE_SYNC()
        __builtin_amdgcn_s_setprio(1);
        MFMA_QUAD(0, 0)
        __builtin_amdgcn_s_setprio(0);
        __builtin_amdgcn_s_barrier();
#pragma unroll
        for (int nq = 0; nq < 2; ++nq) { RD_B(b[nq][0], buf, 1, nq, 0) RD_B(b[nq][1], buf, 1, nq, 1) }
        PHASE_SYNC()
        __builtin_amdgcn_s_setprio(1);
        MFMA_QUAD(0, 1)
        __builtin_amdgcn_s_setprio(0);
        __builtin_amdgcn_s_barrier();
#pragma unroll
        for (int mq = 0; mq < 4; ++mq) { RD_A(a[mq][0], buf, 1, mq, 0) RD_A(a[mq][1], buf, 1, mq, 1) }
        PHASE_SYNC()
        __builtin_amdgcn_s_setprio(1);
        MFMA_QUAD(1, 1)
        __builtin_amdgcn_s_setprio(0);
        __builtin_amdgcn_s_barrier();
#pragma unroll
        for (int nq = 0; nq < 2; ++nq) { RD_B(b[nq][0], buf, 0, nq, 0) RD_B(b[nq][1], buf, 0, nq, 1) }
        PHASE_SYNC()
        __builtin_amdgcn_s_setprio(1);
        MFMA_QUAD(1, 0)
        __builtin_amdgcn_s_setprio(0);
        asm volatile("s_waitcnt vmcnt(0)" ::: "memory");
        __builtin_amdgcn_s_barrier();
    }

#pragma unroll
    for (int m = 0; m < 8; ++m)
#pragma unroll
        for (int n = 0; n < 4; ++n) {
            int row = m0 + (m >> 2) * 128 + wr * 64 + (m & 3) * 16 + kg * 4;
            int col = n0 + (n >> 1) * 128 + wc * 32 + (n & 1) * 16 + r16;
#pragma unroll
            for (int r = 0; r < 4; ++r)
                out[(size_t)(row + r) * HH + col] = fast_tanh(acc[m][n][r]);
        }
}

extern "C" void kernel_launch(void* const* d_in, const int* in_sizes, int n_in,
                              void* d_out, int out_size, void* d_ws, size_t ws_size,
                              hipStream_t stream) {
    const float* enc  = (const float*)d_in[0];   // [64][258][1024]
    const float* ht   = (const float*)d_in[1];   // [64][256][1024]
    const int*   slen = (const int*)d_in[2];     // [64]
    const float* pt   = (const float*)d_in[3];   // [64]
    const float* Wa   = (const float*)d_in[4];   // [1024][1024]
    const float* Wc   = (const float*)d_in[5];   // [1024][2048]
    float* out = (float*)d_out;                  // [64][256][1024] f32

    char* ws = (char*)d_ws;
    int* meta = (int*)(ws + OFF_META);
    unsigned short* wehi = (unsigned short*)(ws + OFF_WEHI);
    unsigned short* welo = (unsigned short*)(ws + OFF_WELO);
    unsigned short* wahi = (unsigned short*)(ws + OFF_WAHI);
    unsigned short* walo = (unsigned short*)(ws + OFF_WALO);
    unsigned short* wcbf = (unsigned short*)(ws + OFF_WCBF);
    unsigned short* hbf  = (unsigned short*)(ws + OFF_HBF);
    unsigned short* uhi  = (unsigned short*)(ws + OFF_UHI);
    unsigned short* ulo  = (unsigned short*)(ws + OFF_ULO);
    unsigned short* ctx  = (unsigned short*)(ws + OFF_CTX);

    hipFuncSetAttribute((const void*)k_out_gemm256,
                        hipFuncAttributeMaxDynamicSharedMemorySize, 131072);

    hipLaunchKernelGGL(k_window, dim3(1), dim3(64), 0, stream, pt, slen, meta);
    hipLaunchKernelGGL(k_split, dim3((HH * HH / 4) / 256), dim3(256), 0, stream,
                       Wa, wahi, walo, HH * HH / 4);
    hipLaunchKernelGGL(k_tobf, dim3((HH * 2 * HH / 4) / 256), dim3(256), 0, stream,
                       Wc, wcbf, HH * 2 * HH / 4);
    hipLaunchKernelGGL(k_tobf, dim3((NB * QQ * HH / 4) / 256), dim3(256), 0, stream,
                       ht, hbf, NB * QQ * HH / 4);
    hipLaunchKernelGGL(k_gather, dim3(MU), dim3(256), 0, stream, enc, meta, wehi, welo);
    hipLaunchKernelGGL(k_ugemm, dim3(HH / 128, MU / 128), dim3(256), 0, stream,
                       wehi, welo, wahi, walo, uhi, ulo);
    hipLaunchKernelGGL(k_attn_mfma, dim3(NB * 8), dim3(256), 0, stream,
                       ht, enc, uhi, ulo, pt, meta, ctx);
    hipLaunchKernelGGL(k_out_gemm256, dim3(256), dim3(512), 131072, stream,
                       ctx, hbf, wcbf, out);
}

// Round 4
// 201.237 us; speedup vs baseline: 1.6489x; 1.2053x over previous
//
#include <hip/hip_runtime.h>
#include <hip/hip_bf16.h>
#include <cstdint>

#define DEVINL __device__ __forceinline__

typedef __attribute__((ext_vector_type(8))) short short8;   // 8 bf16 in 4 VGPRs
typedef __attribute__((ext_vector_type(4))) float f32x4;
typedef __attribute__((ext_vector_type(4))) unsigned short u16x4;

static constexpr int NB = 64, LL = 258, HH = 1024, QQ = 256;
static constexpr int WROWS = 33;          // max window length (2*16+1)
static constexpr int MU = 2176;           // 64*33 = 2112 padded to 17*128
static constexpr int VTN = 4096;          // VT col stride: 64 n * 64 li

// ---- workspace layout (bytes) ----
static constexpr size_t OFF_META = 0;
static constexpr size_t SZ_WE   = (size_t)MU * HH * 2;
static constexpr size_t OFF_WEHI = 1024;
static constexpr size_t OFF_WELO = OFF_WEHI + SZ_WE;
static constexpr size_t OFF_WAHI = OFF_WELO + SZ_WE;
static constexpr size_t OFF_WALO = OFF_WAHI + (size_t)HH * HH * 2;
static constexpr size_t OFF_WCBF = OFF_WALO + (size_t)HH * HH * 2;
static constexpr size_t OFF_HBF  = OFF_WCBF + (size_t)HH * 2 * HH * 2;
static constexpr size_t OFF_U    = OFF_HBF + (size_t)NB * QQ * HH * 2;
static constexpr size_t OFF_UHI  = OFF_U;
static constexpr size_t OFF_ULO  = OFF_U + (size_t)MU * HH * 2;
static constexpr size_t OFF_CTX  = OFF_U + (size_t)MU * HH * 4;   // out_ctx bf16 [16384][1024]
static constexpr size_t OFF_VT   = OFF_CTX + (size_t)NB * QQ * HH * 2;  // VT bf16 [1024][4096]
// total = 101,712,896 B (~97 MiB)

DEVINL unsigned short f2bf(float x) {
    union { float f; uint32_t u; } v; v.f = x;
    uint32_t u = v.u;
    uint32_t r = (u + 0x7FFFu + ((u >> 16) & 1u)) >> 16;
    return (unsigned short)r;
}
DEVINL float bf2f(unsigned short b) {
    union { uint32_t u; float f; } v; v.u = ((uint32_t)b) << 16;
    return v.f;
}

template <typename T>
DEVINL void lds_load16(const T* g, T* l) {
    __builtin_amdgcn_global_load_lds(
        (const __attribute__((address_space(1))) void*)g,
        (__attribute__((address_space(3))) void*)l, 16, 0, 0);
}

DEVINL float fast_tanh(float x) {
    float e = __expf(2.0f * x);
    return 1.0f - 2.0f / (e + 1.0f);
}

// ---------------- K0: per-n window bounds ----------------
__global__ void k_window(const float* __restrict__ pt, const int* __restrict__ slen,
                         int* __restrict__ meta) {
    int n = threadIdx.x;
    if (n >= NB) return;
    float p = pt[n];
    float se = (float)slen[n];
    float s = fmaxf(p - 16.0f, 0.0f);
    float e = fminf(p + 16.0f, se);
    int ls = (int)ceilf(s);
    int le = (int)floorf(e); if (le > LL - 1) le = LL - 1;
    int lc = le - ls + 1;
    if (lc < 0) lc = 0;
    if (lc > WROWS) lc = WROWS;
    meta[n] = ls; meta[64 + n] = lc;
}

// ---------------- K1: f32 -> bf16 hi/lo split ----------------
__global__ __launch_bounds__(256) void k_split(const float* __restrict__ x,
                                               unsigned short* __restrict__ hi,
                                               unsigned short* __restrict__ lo, int count4) {
    int i = blockIdx.x * 256 + threadIdx.x;
    if (i >= count4) return;
    f32x4 v = ((const f32x4*)x)[i];
    u16x4 h, l;
#pragma unroll
    for (int j = 0; j < 4; ++j) {
        unsigned short hb = f2bf(v[j]);
        h[j] = hb;
        l[j] = f2bf(v[j] - bf2f(hb));
    }
    ((u16x4*)hi)[i] = h;
    ((u16x4*)lo)[i] = l;
}

// ---------------- K2: f32 -> bf16 (hi only) ----------------
__global__ __launch_bounds__(256) void k_tobf(const float* __restrict__ x,
                                              unsigned short* __restrict__ hi, int count4) {
    int i = blockIdx.x * 256 + threadIdx.x;
    if (i >= count4) return;
    f32x4 v = ((const f32x4*)x)[i];
    u16x4 h;
#pragma unroll
    for (int j = 0; j < 4; ++j) h[j] = f2bf(v[j]);
    ((u16x4*)hi)[i] = h;
}

// ---------------- K3: gather windowed enc rows -> bf16 hi/lo, zero-pad ----------------
__global__ __launch_bounds__(256) void k_gather(const float* __restrict__ enc,
                                                const int* __restrict__ meta,
                                                unsigned short* __restrict__ whi,
                                                unsigned short* __restrict__ wlo) {
    int r = blockIdx.x;       // 0..2175
    int t = threadIdx.x;
    const float* src = nullptr;
    bool valid = false;
    if (r < NB * WROWS) {
        int n = r / WROWS, li = r - n * WROWS;
        int ls = meta[n], lc = meta[64 + n];
        if (li < lc) { valid = true; src = enc + ((size_t)n * LL + ls + li) * HH; }
    }
    f32x4 v;
    if (valid) v = ((const f32x4*)src)[t];
    else { v[0] = 0.f; v[1] = 0.f; v[2] = 0.f; v[3] = 0.f; }
    u16x4 h, l;
#pragma unroll
    for (int j = 0; j < 4; ++j) {
        unsigned short hb = f2bf(v[j]);
        h[j] = hb;
        l[j] = f2bf(v[j] - bf2f(hb));
    }
    size_t o = (size_t)r * HH / 4 + t;
    ((u16x4*)whi)[o] = h;
    ((u16x4*)wlo)[o] = l;
}

// ---------------- K4: U = we @ W_a^T  (3-term split bf16 MFMA, bf16 hi/lo out) ----------------
__global__ __launch_bounds__(256) void k_ugemm(const unsigned short* __restrict__ Ahi,
                                               const unsigned short* __restrict__ Alo,
                                               const unsigned short* __restrict__ Bhi,
                                               const unsigned short* __restrict__ Blo,
                                               unsigned short* __restrict__ Uhi,
                                               unsigned short* __restrict__ Ulo) {
    constexpr int BK = 32;
    __shared__ unsigned short sAh[128 * BK], sAl[128 * BK], sBh[128 * BK], sBl[128 * BK];
    int tid = threadIdx.x;
    int w = tid >> 6, lane = tid & 63;
    int m0 = blockIdx.y * 128, n0 = blockIdx.x * 128;
    int wr = w >> 1, wc = w & 1;
    int srow = lane >> 2, slot = lane & 3;
    int r16 = lane & 15, khalf = lane >> 4;
    f32x4 acc[4][4] = {};

    for (int kb = 0; kb < 1024; kb += BK) {
        __syncthreads();
#pragma unroll
        for (int i = 0; i < 2; ++i) {
            int chunk = w * 2 + i;
            int trow = chunk * 16 + srow;
            int gcol = kb + slot * 8;
            size_t aoff = (size_t)(m0 + trow) * HH + gcol;
            size_t boff = (size_t)(n0 + trow) * HH + gcol;
            lds_load16(Ahi + aoff, &sAh[chunk * 512]);
            lds_load16(Alo + aoff, &sAl[chunk * 512]);
            lds_load16(Bhi + boff, &sBh[chunk * 512]);
            lds_load16(Blo + boff, &sBl[chunk * 512]);
        }
        asm volatile("s_waitcnt vmcnt(0)" ::: "memory");
        __syncthreads();

        short8 ah[4], al[4], bh[4], bl[4];
#pragma unroll
        for (int f = 0; f < 4; ++f) {
            int ai = (wr * 64 + f * 16 + r16) * BK + khalf * 8;
            ah[f] = *(const short8*)&sAh[ai];
            al[f] = *(const short8*)&sAl[ai];
            int bi = (wc * 64 + f * 16 + r16) * BK + khalf * 8;
            bh[f] = *(const short8*)&sBh[bi];
            bl[f] = *(const short8*)&sBl[bi];
        }
#pragma unroll
        for (int mf = 0; mf < 4; ++mf)
#pragma unroll
            for (int nf = 0; nf < 4; ++nf) {
                acc[mf][nf] = __builtin_amdgcn_mfma_f32_16x16x32_bf16(ah[mf], bh[nf], acc[mf][nf], 0, 0, 0);
                acc[mf][nf] = __builtin_amdgcn_mfma_f32_16x16x32_bf16(ah[mf], bl[nf], acc[mf][nf], 0, 0, 0);
                acc[mf][nf] = __builtin_amdgcn_mfma_f32_16x16x32_bf16(al[mf], bh[nf], acc[mf][nf], 0, 0, 0);
            }
    }
    int rg = lane >> 4;
#pragma unroll
    for (int mf = 0; mf < 4; ++mf)
#pragma unroll
        for (int nf = 0; nf < 4; ++nf)
#pragma unroll
            for (int r = 0; r < 4; ++r) {
                int m = m0 + wr * 64 + mf * 16 + rg * 4 + r;
                int nn = n0 + wc * 64 + nf * 16 + r16;
                float v = acc[mf][nf][r];
                unsigned short h = f2bf(v);
                Uhi[(size_t)m * HH + nn] = h;
                Ulo[(size_t)m * HH + nn] = f2bf(v - bf2f(h));
            }
}

// ---------------- K4b: VT = Wc1 @ we^T  (2-term we-split, bf16 out, [o][n*64+li]) ----------------
// M = o (1024, A = wcbf rows stride 2048 cols 0..1023), N = we-row (2176, B^T = we rows).
__global__ __launch_bounds__(256) void k_vgemm(const unsigned short* __restrict__ Wc1,
                                               const unsigned short* __restrict__ Bhi,
                                               const unsigned short* __restrict__ Blo,
                                               unsigned short* __restrict__ VT) {
    constexpr int BK = 32;
    __shared__ unsigned short sA[128 * BK], sBh[128 * BK], sBl[128 * BK];
    int tid = threadIdx.x;
    int w = tid >> 6, lane = tid & 63;
    int m0 = blockIdx.y * 128, n0 = blockIdx.x * 128;
    int wr = w >> 1, wc = w & 1;
    int srow = lane >> 2, slot = lane & 3;
    int r16 = lane & 15, khalf = lane >> 4;
    f32x4 acc[4][4] = {};

    for (int kb = 0; kb < 1024; kb += BK) {
        __syncthreads();
#pragma unroll
        for (int i = 0; i < 2; ++i) {
            int chunk = w * 2 + i;
            int trow = chunk * 16 + srow;
            int gcol = kb + slot * 8;
            lds_load16(Wc1 + (size_t)(m0 + trow) * (2 * HH) + gcol, &sA[chunk * 512]);
            lds_load16(Bhi + (size_t)(n0 + trow) * HH + gcol, &sBh[chunk * 512]);
            lds_load16(Blo + (size_t)(n0 + trow) * HH + gcol, &sBl[chunk * 512]);
        }
        asm volatile("s_waitcnt vmcnt(0)" ::: "memory");
        __syncthreads();

        short8 af[4], bh[4], bl[4];
#pragma unroll
        for (int f = 0; f < 4; ++f) {
            af[f] = *(const short8*)&sA[(wr * 64 + f * 16 + r16) * BK + khalf * 8];
            int bi = (wc * 64 + f * 16 + r16) * BK + khalf * 8;
            bh[f] = *(const short8*)&sBh[bi];
            bl[f] = *(const short8*)&sBl[bi];
        }
#pragma unroll
        for (int mf = 0; mf < 4; ++mf)
#pragma unroll
            for (int nf = 0; nf < 4; ++nf) {
                acc[mf][nf] = __builtin_amdgcn_mfma_f32_16x16x32_bf16(af[mf], bh[nf], acc[mf][nf], 0, 0, 0);
                acc[mf][nf] = __builtin_amdgcn_mfma_f32_16x16x32_bf16(af[mf], bl[nf], acc[mf][nf], 0, 0, 0);
            }
    }
    int rg = lane >> 4;
#pragma unroll
    for (int mf = 0; mf < 4; ++mf)
#pragma unroll
        for (int nf = 0; nf < 4; ++nf)
#pragma unroll
            for (int r = 0; r < 4; ++r) {
                int o = m0 + wr * 64 + mf * 16 + rg * 4 + r;
                int wrow = n0 + wc * 64 + nf * 16 + r16;
                int n = wrow / WROWS, li = wrow - n * WROWS;
                if (n < NB)
                    VT[(size_t)o * VTN + n * 64 + li] = f2bf(acc[mf][nf][r]);
            }
}

// ---------------- K5: fused attention: score + softmax + gauss + P@VT ----------------
// One block per (n, 32-q slice). 4 waves.
__global__ __launch_bounds__(256) void k_attn2(const float* __restrict__ ht,
                                               const unsigned short* __restrict__ Uhi,
                                               const unsigned short* __restrict__ Ulo,
                                               const unsigned short* __restrict__ VT,
                                               const float* __restrict__ pt,
                                               const int* __restrict__ meta,
                                               unsigned short* __restrict__ ctx) {
    __shared__ float sPart[4][32 * 48];
    __shared__ float sScore[32 * 48];
    __shared__ unsigned short sPhi[32 * 72];
    __shared__ unsigned short sPlo[32 * 72];

    const int tid = threadIdx.x;
    const int w = tid >> 6, lane = tid & 63;
    const int n = blockIdx.x >> 3, q0 = (blockIdx.x & 7) * 32;
    const int ls = meta[n], lc = meta[64 + n];
    const float p = pt[n];
    const int r16 = lane & 15, khalf = lane >> 4, rg = lane >> 4;

    const float* hbase = ht + ((size_t)(n * QQ + q0)) * HH;
    const unsigned short* uhbase = Uhi + (size_t)n * WROWS * HH;
    const unsigned short* ulbase = Ulo + (size_t)n * WROWS * HH;

    // ---- Phase A: score partials, K split over waves (3-term hi/lo) ----
    f32x4 acc[2][3] = {};
    for (int ks = 0; ks < 8; ++ks) {
        int kcol = w * 256 + ks * 32 + khalf * 8;
        short8 ah[2], al[2];
#pragma unroll
        for (int mf = 0; mf < 2; ++mf) {
            const float* src = hbase + (size_t)(mf * 16 + r16) * HH + kcol;
            f32x4 v0 = *(const f32x4*)src;
            f32x4 v1 = *(const f32x4*)(src + 4);
            float vv[8] = {v0[0], v0[1], v0[2], v0[3], v1[0], v1[1], v1[2], v1[3]};
#pragma unroll
            for (int j = 0; j < 8; ++j) {
                unsigned short hb = f2bf(vv[j]);
                ah[mf][j] = (short)hb;
                al[mf][j] = (short)f2bf(vv[j] - bf2f(hb));
            }
        }
#pragma unroll
        for (int nf = 0; nf < 3; ++nf) {
            size_t uoff = (size_t)(nf * 16 + r16) * HH + kcol;
            short8 bh = *(const short8*)(uhbase + uoff);
            short8 bl = *(const short8*)(ulbase + uoff);
#pragma unroll
            for (int mf = 0; mf < 2; ++mf) {
                acc[mf][nf] = __builtin_amdgcn_mfma_f32_16x16x32_bf16(ah[mf], bh, acc[mf][nf], 0, 0, 0);
                acc[mf][nf] = __builtin_amdgcn_mfma_f32_16x16x32_bf16(ah[mf], bl, acc[mf][nf], 0, 0, 0);
                acc[mf][nf] = __builtin_amdgcn_mfma_f32_16x16x32_bf16(al[mf], bh, acc[mf][nf], 0, 0, 0);
            }
        }
    }
#pragma unroll
    for (int mf = 0; mf < 2; ++mf)
#pragma unroll
        for (int nf = 0; nf < 3; ++nf)
#pragma unroll
            for (int r = 0; r < 4; ++r)
                sPart[w][(mf * 16 + rg * 4 + r) * 48 + nf * 16 + r16] = acc[mf][nf][r];
    __syncthreads();

    // ---- reduce + softmax + gauss ----
    {
        int q = tid >> 3, g = tid & 7;
        float sc6[6];
#pragma unroll
        for (int s = 0; s < 6; ++s) {
            int li = g + 8 * s;
            int o = q * 48 + li;
            sc6[s] = sPart[0][o] + sPart[1][o] + sPart[2][o] + sPart[3][o];
        }
        float mx = -1e30f;
#pragma unroll
        for (int s = 0; s < 6; ++s) { int li = g + 8 * s; if (li < lc) mx = fmaxf(mx, sc6[s]); }
        for (int off = 1; off < 8; off <<= 1) mx = fmaxf(mx, __shfl_xor(mx, off, 8));
        float sum = 0.f, ex[6];
#pragma unroll
        for (int s = 0; s < 6; ++s) {
            int li = g + 8 * s;
            float e = (li < lc) ? __expf(sc6[s] - mx) : 0.f;
            ex[s] = e; sum += e;
        }
        for (int off = 1; off < 8; off <<= 1) sum += __shfl_xor(sum, off, 8);
        float inv = 1.0f / sum;
#pragma unroll
        for (int s = 0; s < 6; ++s) {
            int li = g + 8 * s;
            float d = (float)(ls + li) - p;
            float gs = __expf(-(d * d) * (1.0f / 128.0f));
            sScore[q * 48 + li] = ex[s] * inv * gs;
        }
    }
    __syncthreads();

    // ---- split P into hi/lo bf16 [32][64] (cols 48..63 = 0) ----
    {
        int row = tid >> 3, c0 = (tid & 7) * 8;
#pragma unroll
        for (int j = 0; j < 8; ++j) {
            int c = c0 + j;
            float pv = (c < 48) ? sScore[row * 48 + c] : 0.f;
            unsigned short hb = f2bf(pv);
            sPhi[row * 72 + c] = hb;
            sPlo[row * 72 + c] = f2bf(pv - bf2f(hb));
        }
    }
    __syncthreads();

    // ---- Phase B: out_ctx[32][1024] = P @ V via VT[o][n*64+li]. Waves split o into 4x256. ----
    short8 pa[2][2], plq[2][2];
#pragma unroll
    for (int mf = 0; mf < 2; ++mf)
#pragma unroll
        for (int ks = 0; ks < 2; ++ks) {
            pa[mf][ks]  = *(const short8*)&sPhi[(mf * 16 + r16) * 72 + ks * 32 + khalf * 8];
            plq[mf][ks] = *(const short8*)&sPlo[(mf * 16 + r16) * 72 + ks * 32 + khalf * 8];
        }
    const unsigned short* vtb = VT + n * 64 + khalf * 8;
#pragma unroll
    for (int half = 0; half < 2; ++half) {
        f32x4 accB[2][8] = {};
        const int hcol0 = w * 256 + half * 128;
#pragma unroll
        for (int nf = 0; nf < 8; ++nf) {
            const int o = hcol0 + nf * 16 + r16;
#pragma unroll
            for (int ks = 0; ks < 2; ++ks) {
                short8 bfrag = *(const short8*)(vtb + (size_t)o * VTN + ks * 32);
#pragma unroll
                for (int mf = 0; mf < 2; ++mf) {
                    accB[mf][nf] = __builtin_amdgcn_mfma_f32_16x16x32_bf16(pa[mf][ks], bfrag, accB[mf][nf], 0, 0, 0);
                    accB[mf][nf] = __builtin_amdgcn_mfma_f32_16x16x32_bf16(plq[mf][ks], bfrag, accB[mf][nf], 0, 0, 0);
                }
            }
        }
#pragma unroll
        for (int mf = 0; mf < 2; ++mf)
#pragma unroll
            for (int nf = 0; nf < 8; ++nf)
#pragma unroll
                for (int r = 0; r < 4; ++r)
                    ctx[(size_t)(n * QQ + q0 + mf * 16 + rg * 4 + r) * HH + hcol0 + nf * 16 + r16] =
                        f2bf(accB[mf][nf][r]);
    }
}

// ---------------- K6: out = tanh(h @ Wc2^T + out_ctx), K=1024, 256^2 8-phase ----------------
#define RD_A(dst, buf, mh, mq, ksub) \
    dst = *(const short8*)&sA[(buf) * 16384 + (mh) * 8192 + \
        (wr * 64 + (mq) * 16 + r16) * 64 + ((((ksub) * 4 + kg) ^ (r16 & 7)) * 8)];
#define RD_B(dst, buf, nh, nq, ksub) \
    dst = *(const short8*)&sB[(buf) * 16384 + (nh) * 8192 + \
        (wc * 32 + (nq) * 16 + r16) * 64 + ((((ksub) * 4 + kg) ^ (r16 & 7)) * 8)];
#define MFMA_QUAD(MH, NH) \
    _Pragma("unroll") \
    for (int mq = 0; mq < 4; ++mq) { \
        _Pragma("unroll") \
        for (int nq = 0; nq < 2; ++nq) { \
            f32x4 c = acc[(MH) * 4 + mq][(NH) * 2 + nq]; \
            c = __builtin_amdgcn_mfma_f32_16x16x32_bf16(a[mq][0], b[nq][0], c, 0, 0, 0); \
            c = __builtin_amdgcn_mfma_f32_16x16x32_bf16(a[mq][1], b[nq][1], c, 0, 0, 0); \
            acc[(MH) * 4 + mq][(NH) * 2 + nq] = c; \
        } \
    }
#define PHASE_SYNC() \
    __builtin_amdgcn_s_barrier(); \
    asm volatile("s_waitcnt lgkmcnt(0)" ::: "memory"); \
    __builtin_amdgcn_sched_barrier(0);

__global__ __launch_bounds__(512, 1) void k_out_gemm256(
    const unsigned short* __restrict__ Ahf,
    const unsigned short* __restrict__ Bt,
    const unsigned short* __restrict__ Cadd,
    float* __restrict__ out) {
    extern __shared__ unsigned short lds[];
    unsigned short* sA = lds;          // [2 buf][2 half][128*64]
    unsigned short* sB = lds + 32768;

    const int tid = threadIdx.x;
    const int wid = tid >> 6, lane = tid & 63;
    const int bid = blockIdx.x;
    const int swz = (bid & 7) * 32 + (bid >> 3);
    const int mt = swz >> 2, ntile = swz & 3;
    const int m0 = mt * 256, n0 = ntile * 256;
    const int wr = wid >> 2, wc = wid & 3;
    const int r16 = lane & 15, kg = lane >> 4;

    const int srow = lane >> 3;
    const int kswz = ((lane & 7) ^ srow) * 8;

    f32x4 acc[8][4] = {};

    auto stage_tile = [&](int buf, int kb) {
#pragma unroll
        for (int half = 0; half < 2; ++half)
#pragma unroll
            for (int i = 0; i < 2; ++i) {
                int r = half * 128 + i * 64 + wid * 8 + srow;
                lds_load16(Ahf + (size_t)(m0 + r) * HH + kb + kswz,
                           sA + buf * 16384 + half * 8192 + i * 4096 + wid * 512);
            }
#pragma unroll
        for (int half = 0; half < 2; ++half)
#pragma unroll
            for (int i = 0; i < 2; ++i) {
                int r = half * 128 + i * 64 + wid * 8 + srow;
                lds_load16(Bt + (size_t)(n0 + r) * (2 * HH) + 1024 + kb + kswz,
                           sB + buf * 16384 + half * 8192 + i * 4096 + wid * 512);
            }
    };

    stage_tile(0, 0);
    asm volatile("s_waitcnt vmcnt(0)" ::: "memory");
    __builtin_amdgcn_s_barrier();

    short8 a[4][2], b[2][2];
    for (int t = 0; t < 16; ++t) {
        const int buf = t & 1;
#pragma unroll
        for (int mq = 0; mq < 4; ++mq) { RD_A(a[mq][0], buf, 0, mq, 0) RD_A(a[mq][1], buf, 0, mq, 1) }
#pragma unroll
        for (int nq = 0; nq < 2; ++nq) { RD_B(b[nq][0], buf, 0, nq, 0) RD_B(b[nq][1], buf, 0, nq, 1) }
        if (t + 1 < 16) stage_tile(buf ^ 1, (t + 1) * 64);
        PHASE_SYNC()
        __builtin_amdgcn_s_setprio(1);
        MFMA_QUAD(0, 0)
        __builtin_amdgcn_s_setprio(0);
        __builtin_amdgcn_s_barrier();
#pragma unroll
        for (int nq = 0; nq < 2; ++nq) { RD_B(b[nq][0], buf, 1, nq, 0) RD_B(b[nq][1], buf, 1, nq, 1) }
        PHASE_SYNC()
        __builtin_amdgcn_s_setprio(1);
        MFMA_QUAD(0, 1)
        __builtin_amdgcn_s_setprio(0);
        __builtin_amdgcn_s_barrier();
#pragma unroll
        for (int mq = 0; mq < 4; ++mq) { RD_A(a[mq][0], buf, 1, mq, 0) RD_A(a[mq][1], buf, 1, mq, 1) }
        PHASE_SYNC()
        __builtin_amdgcn_s_setprio(1);
        MFMA_QUAD(1, 1)
        __builtin_amdgcn_s_setprio(0);
        __builtin_amdgcn_s_barrier();
#pragma unroll
        for (int nq = 0; nq < 2; ++nq) { RD_B(b[nq][0], buf, 0, nq, 0) RD_B(b[nq][1], buf, 0, nq, 1) }
        PHASE_SYNC()
        __builtin_amdgcn_s_setprio(1);
        MFMA_QUAD(1, 0)
        __builtin_amdgcn_s_setprio(0);
        asm volatile("s_waitcnt vmcnt(0)" ::: "memory");
        __builtin_amdgcn_s_barrier();
    }

#pragma unroll
    for (int m = 0; m < 8; ++m)
#pragma unroll
        for (int n = 0; n < 4; ++n) {
            int row = m0 + (m >> 2) * 128 + wr * 64 + (m & 3) * 16 + kg * 4;
            int col = n0 + (n >> 1) * 128 + wc * 32 + (n & 1) * 16 + r16;
#pragma unroll
            for (int r = 0; r < 4; ++r) {
                float cadd = bf2f(Cadd[(size_t)(row + r) * HH + col]);
                out[(size_t)(row + r) * HH + col] = fast_tanh(acc[m][n][r] + cadd);
            }
        }
}

extern "C" void kernel_launch(void* const* d_in, const int* in_sizes, int n_in,
                              void* d_out, int out_size, void* d_ws, size_t ws_size,
                              hipStream_t stream) {
    const float* enc  = (const float*)d_in[0];
    const float* ht   = (const float*)d_in[1];
    const int*   slen = (const int*)d_in[2];
    const float* pt   = (const float*)d_in[3];
    const float* Wa   = (const float*)d_in[4];
    const float* Wc   = (const float*)d_in[5];
    float* out = (float*)d_out;

    char* ws = (char*)d_ws;
    int* meta = (int*)(ws + OFF_META);
    unsigned short* wehi = (unsigned short*)(ws + OFF_WEHI);
    unsigned short* welo = (unsigned short*)(ws + OFF_WELO);
    unsigned short* wahi = (unsigned short*)(ws + OFF_WAHI);
    unsigned short* walo = (unsigned short*)(ws + OFF_WALO);
    unsigned short* wcbf = (unsigned short*)(ws + OFF_WCBF);
    unsigned short* hbf  = (unsigned short*)(ws + OFF_HBF);
    unsigned short* uhi  = (unsigned short*)(ws + OFF_UHI);
    unsigned short* ulo  = (unsigned short*)(ws + OFF_ULO);
    unsigned short* ctx  = (unsigned short*)(ws + OFF_CTX);
    unsigned short* vt   = (unsigned short*)(ws + OFF_VT);

    hipFuncSetAttribute((const void*)k_out_gemm256,
                        hipFuncAttributeMaxDynamicSharedMemorySize, 131072);

    hipLaunchKernelGGL(k_window, dim3(1), dim3(64), 0, stream, pt, slen, meta);
    hipLaunchKernelGGL(k_split, dim3((HH * HH / 4) / 256), dim3(256), 0, stream,
                       Wa, wahi, walo, HH * HH / 4);
    hipLaunchKernelGGL(k_tobf, dim3((HH * 2 * HH / 4) / 256), dim3(256), 0, stream,
                       Wc, wcbf, HH * 2 * HH / 4);
    hipLaunchKernelGGL(k_tobf, dim3((NB * QQ * HH / 4) / 256), dim3(256), 0, stream,
                       ht, hbf, NB * QQ * HH / 4);
    hipLaunchKernelGGL(k_gather, dim3(MU), dim3(256), 0, stream, enc, meta, wehi, welo);
    hipLaunchKernelGGL(k_ugemm, dim3(HH / 128, MU / 128), dim3(256), 0, stream,
                       wehi, welo, wahi, walo, uhi, ulo);
    hipLaunchKernelGGL(k_vgemm, dim3(MU / 128, HH / 128), dim3(256), 0, stream,
                       wcbf, wehi, welo, vt);
    hipLaunchKernelGGL(k_attn2, dim3(NB * 8), dim3(256), 0, stream,
                       ht, uhi, ulo, vt, pt, meta, ctx);
    hipLaunchKernelGGL(k_out_gemm256, dim3(256), dim3(512), 131072, stream,
                       hbf, wcbf, ctx, out);
}

// Round 5
// 170.313 us; speedup vs baseline: 1.9483x; 1.1816x over previous
//
#include <hip/hip_runtime.h>
#include <hip/hip_bf16.h>
#include <cstdint>

#define DEVINL __device__ __forceinline__

typedef __attribute__((ext_vector_type(8))) short short8;   // 8 bf16 in 4 VGPRs
typedef __attribute__((ext_vector_type(4))) float f32x4;
typedef __attribute__((ext_vector_type(4))) unsigned short u16x4;

static constexpr int NB = 64, LL = 258, HH = 1024, QQ = 256;
static constexpr int WROWS = 33;          // max window length (2*16+1)
static constexpr int MU = 2176;           // 64*33 = 2112 padded to 17*128
static constexpr int VTN = 4096;          // VT col stride: 64 n * 64 li

// ---- workspace layout (bytes) ----
static constexpr size_t OFF_META = 0;
static constexpr size_t SZ_WE   = (size_t)MU * HH * 2;
static constexpr size_t OFF_WEHI = 1024;
static constexpr size_t OFF_WELO = OFF_WEHI + SZ_WE;
static constexpr size_t OFF_WAHI = OFF_WELO + SZ_WE;
static constexpr size_t OFF_WALO = OFF_WAHI + (size_t)HH * HH * 2;
static constexpr size_t OFF_WCBF = OFF_WALO + (size_t)HH * HH * 2;
static constexpr size_t OFF_HBF  = OFF_WCBF + (size_t)HH * 2 * HH * 2;
static constexpr size_t OFF_U    = OFF_HBF + (size_t)NB * QQ * HH * 2;
static constexpr size_t OFF_UHI  = OFF_U;
static constexpr size_t OFF_ULO  = OFF_U + (size_t)MU * HH * 2;
static constexpr size_t OFF_CTX  = OFF_U + (size_t)MU * HH * 4;
static constexpr size_t OFF_VT   = OFF_CTX + (size_t)NB * QQ * HH * 2;  // VT bf16 [1024][4096]

DEVINL unsigned short f2bf(float x) {
    union { float f; uint32_t u; } v; v.f = x;
    uint32_t u = v.u;
    uint32_t r = (u + 0x7FFFu + ((u >> 16) & 1u)) >> 16;
    return (unsigned short)r;
}
DEVINL float bf2f(unsigned short b) {
    union { uint32_t u; float f; } v; v.u = ((uint32_t)b) << 16;
    return v.f;
}

template <typename T>
DEVINL void lds_load16(const T* g, T* l) {
    __builtin_amdgcn_global_load_lds(
        (const __attribute__((address_space(1))) void*)g,
        (__attribute__((address_space(3))) void*)l, 16, 0, 0);
}

DEVINL float fast_tanh(float x) {
    float e = __expf(2.0f * x);
    return 1.0f - 2.0f / (e + 1.0f);
}

// ---------------- K0: per-n window bounds ----------------
__global__ void k_window(const float* __restrict__ pt, const int* __restrict__ slen,
                         int* __restrict__ meta) {
    int n = threadIdx.x;
    if (n >= NB) return;
    float p = pt[n];
    float se = (float)slen[n];
    float s = fmaxf(p - 16.0f, 0.0f);
    float e = fminf(p + 16.0f, se);
    int ls = (int)ceilf(s);
    int le = (int)floorf(e); if (le > LL - 1) le = LL - 1;
    int lc = le - ls + 1;
    if (lc < 0) lc = 0;
    if (lc > WROWS) lc = WROWS;
    meta[n] = ls; meta[64 + n] = lc;
}

// ---------------- K1: f32 -> bf16 hi/lo split ----------------
__global__ __launch_bounds__(256) void k_split(const float* __restrict__ x,
                                               unsigned short* __restrict__ hi,
                                               unsigned short* __restrict__ lo, int count4) {
    int i = blockIdx.x * 256 + threadIdx.x;
    if (i >= count4) return;
    f32x4 v = ((const f32x4*)x)[i];
    u16x4 h, l;
#pragma unroll
    for (int j = 0; j < 4; ++j) {
        unsigned short hb = f2bf(v[j]);
        h[j] = hb;
        l[j] = f2bf(v[j] - bf2f(hb));
    }
    ((u16x4*)hi)[i] = h;
    ((u16x4*)lo)[i] = l;
}

// ---------------- K2: f32 -> bf16 (hi only) ----------------
__global__ __launch_bounds__(256) void k_tobf(const float* __restrict__ x,
                                              unsigned short* __restrict__ hi, int count4) {
    int i = blockIdx.x * 256 + threadIdx.x;
    if (i >= count4) return;
    f32x4 v = ((const f32x4*)x)[i];
    u16x4 h;
#pragma unroll
    for (int j = 0; j < 4; ++j) h[j] = f2bf(v[j]);
    ((u16x4*)hi)[i] = h;
}

// ---------------- K3: gather windowed enc rows -> bf16 hi/lo, zero-pad ----------------
__global__ __launch_bounds__(256) void k_gather(const float* __restrict__ enc,
                                                const int* __restrict__ meta,
                                                unsigned short* __restrict__ whi,
                                                unsigned short* __restrict__ wlo) {
    int r = blockIdx.x;       // 0..2175
    int t = threadIdx.x;
    const float* src = nullptr;
    bool valid = false;
    if (r < NB * WROWS) {
        int n = r / WROWS, li = r - n * WROWS;
        int ls = meta[n], lc = meta[64 + n];
        if (li < lc) { valid = true; src = enc + ((size_t)n * LL + ls + li) * HH; }
    }
    f32x4 v;
    if (valid) v = ((const f32x4*)src)[t];
    else { v[0] = 0.f; v[1] = 0.f; v[2] = 0.f; v[3] = 0.f; }
    u16x4 h, l;
#pragma unroll
    for (int j = 0; j < 4; ++j) {
        unsigned short hb = f2bf(v[j]);
        h[j] = hb;
        l[j] = f2bf(v[j] - bf2f(hb));
    }
    size_t o = (size_t)r * HH / 4 + t;
    ((u16x4*)whi)[o] = h;
    ((u16x4*)wlo)[o] = l;
}

// ---------------- K4: U = we @ W_a^T  (64x64 tile, dbuf 2-phase counted, 3-term) ----------------
// grid (N/64=16, MU/64=34). 4 waves 2x2, each 32x32 out. K-slot XOR swizzle (2-way banks).
__global__ __launch_bounds__(256) void k_ugemm64(const unsigned short* __restrict__ Ahi,
                                                 const unsigned short* __restrict__ Alo,
                                                 const unsigned short* __restrict__ Bhi,
                                                 const unsigned short* __restrict__ Blo,
                                                 unsigned short* __restrict__ Uhi,
                                                 unsigned short* __restrict__ Ulo) {
    __shared__ unsigned short sAh[2][64 * 32], sAl[2][64 * 32], sBh[2][64 * 32], sBl[2][64 * 32];
    const int tid = threadIdx.x;
    const int w = tid >> 6, lane = tid & 63;
    const int m0 = blockIdx.y * 64, n0 = blockIdx.x * 64;
    const int wr = w >> 1, wc = w & 1;
    const int r16 = lane & 15, khalf = lane >> 4;
    const int srow = tid >> 2;                                  // 0..63
    const int scol = ((tid & 3) ^ ((tid >> 3) & 3)) * 8;        // swizzled source k-slot
    const int ldso = tid * 8;                                   // linear dest (elems)
    const int kslot = (khalf ^ ((r16 >> 1) & 3)) * 8;           // swizzled read k-slot
    f32x4 acc[2][2] = {};

    auto stage = [&](int buf, int kb) {
        lds_load16(Ahi + (size_t)(m0 + srow) * HH + kb + scol, &sAh[buf][ldso]);
        lds_load16(Alo + (size_t)(m0 + srow) * HH + kb + scol, &sAl[buf][ldso]);
        lds_load16(Bhi + (size_t)(n0 + srow) * HH + kb + scol, &sBh[buf][ldso]);
        lds_load16(Blo + (size_t)(n0 + srow) * HH + kb + scol, &sBl[buf][ldso]);
    };

    stage(0, 0);
    for (int t = 0; t < 32; ++t) {
        const int buf = t & 1;
        asm volatile("s_waitcnt vmcnt(0)" ::: "memory");
        __builtin_amdgcn_s_barrier();
        short8 ah[2], al[2], bh[2], bl[2];
#pragma unroll
        for (int f = 0; f < 2; ++f) {
            int ai = (wr * 32 + f * 16 + r16) * 32 + kslot;
            ah[f] = *(const short8*)&sAh[buf][ai];
            al[f] = *(const short8*)&sAl[buf][ai];
            int bi = (wc * 32 + f * 16 + r16) * 32 + kslot;
            bh[f] = *(const short8*)&sBh[buf][bi];
            bl[f] = *(const short8*)&sBl[buf][bi];
        }
        if (t + 1 < 32) stage(buf ^ 1, (t + 1) * 32);
        asm volatile("s_waitcnt lgkmcnt(0)" ::: "memory");
        __builtin_amdgcn_sched_barrier(0);
#pragma unroll
        for (int mf = 0; mf < 2; ++mf)
#pragma unroll
            for (int nf = 0; nf < 2; ++nf) {
                acc[mf][nf] = __builtin_amdgcn_mfma_f32_16x16x32_bf16(ah[mf], bh[nf], acc[mf][nf], 0, 0, 0);
                acc[mf][nf] = __builtin_amdgcn_mfma_f32_16x16x32_bf16(ah[mf], bl[nf], acc[mf][nf], 0, 0, 0);
                acc[mf][nf] = __builtin_amdgcn_mfma_f32_16x16x32_bf16(al[mf], bh[nf], acc[mf][nf], 0, 0, 0);
            }
        __builtin_amdgcn_s_barrier();
    }
    const int rg = lane >> 4;
#pragma unroll
    for (int mf = 0; mf < 2; ++mf)
#pragma unroll
        for (int nf = 0; nf < 2; ++nf)
#pragma unroll
            for (int r = 0; r < 4; ++r) {
                int m = m0 + wr * 32 + mf * 16 + rg * 4 + r;
                int nn = n0 + wc * 32 + nf * 16 + r16;
                float v = acc[mf][nf][r];
                unsigned short h = f2bf(v);
                Uhi[(size_t)m * HH + nn] = h;
                Ulo[(size_t)m * HH + nn] = f2bf(v - bf2f(h));
            }
}

// ---------------- K4b: VT = Wc1 @ we^T  (64x64 tile, dbuf 2-phase counted, 2-term) ----------------
// grid (MU/64=34, HH/64=16). Output [o][n*64+li] bf16.
__global__ __launch_bounds__(256) void k_vgemm64(const unsigned short* __restrict__ Wc1,
                                                 const unsigned short* __restrict__ Bhi,
                                                 const unsigned short* __restrict__ Blo,
                                                 unsigned short* __restrict__ VT) {
    __shared__ unsigned short sA[2][64 * 32], sBh[2][64 * 32], sBl[2][64 * 32];
    const int tid = threadIdx.x;
    const int w = tid >> 6, lane = tid & 63;
    const int m0 = blockIdx.y * 64, n0 = blockIdx.x * 64;
    const int wr = w >> 1, wc = w & 1;
    const int r16 = lane & 15, khalf = lane >> 4;
    const int srow = tid >> 2;
    const int scol = ((tid & 3) ^ ((tid >> 3) & 3)) * 8;
    const int ldso = tid * 8;
    const int kslot = (khalf ^ ((r16 >> 1) & 3)) * 8;
    f32x4 acc[2][2] = {};

    auto stage = [&](int buf, int kb) {
        lds_load16(Wc1 + (size_t)(m0 + srow) * (2 * HH) + kb + scol, &sA[buf][ldso]);
        lds_load16(Bhi + (size_t)(n0 + srow) * HH + kb + scol, &sBh[buf][ldso]);
        lds_load16(Blo + (size_t)(n0 + srow) * HH + kb + scol, &sBl[buf][ldso]);
    };

    stage(0, 0);
    for (int t = 0; t < 32; ++t) {
        const int buf = t & 1;
        asm volatile("s_waitcnt vmcnt(0)" ::: "memory");
        __builtin_amdgcn_s_barrier();
        short8 af[2], bh[2], bl[2];
#pragma unroll
        for (int f = 0; f < 2; ++f) {
            af[f] = *(const short8*)&sA[buf][(wr * 32 + f * 16 + r16) * 32 + kslot];
            int bi = (wc * 32 + f * 16 + r16) * 32 + kslot;
            bh[f] = *(const short8*)&sBh[buf][bi];
            bl[f] = *(const short8*)&sBl[buf][bi];
        }
        if (t + 1 < 32) stage(buf ^ 1, (t + 1) * 32);
        asm volatile("s_waitcnt lgkmcnt(0)" ::: "memory");
        __builtin_amdgcn_sched_barrier(0);
#pragma unroll
        for (int mf = 0; mf < 2; ++mf)
#pragma unroll
            for (int nf = 0; nf < 2; ++nf) {
                acc[mf][nf] = __builtin_amdgcn_mfma_f32_16x16x32_bf16(af[mf], bh[nf], acc[mf][nf], 0, 0, 0);
                acc[mf][nf] = __builtin_amdgcn_mfma_f32_16x16x32_bf16(af[mf], bl[nf], acc[mf][nf], 0, 0, 0);
            }
        __builtin_amdgcn_s_barrier();
    }
    const int rg = lane >> 4;
#pragma unroll
    for (int mf = 0; mf < 2; ++mf)
#pragma unroll
        for (int nf = 0; nf < 2; ++nf)
#pragma unroll
            for (int r = 0; r < 4; ++r) {
                int o = m0 + wr * 32 + mf * 16 + rg * 4 + r;
                int wrow = n0 + wc * 32 + nf * 16 + r16;
                int n = wrow / WROWS, li = wrow - n * WROWS;
                if (n < NB)
                    VT[(size_t)o * VTN + n * 64 + li] = f2bf(acc[mf][nf][r]);
            }
}

// ---------------- K5: fused attention: score + softmax + gauss + P@VT ----------------
__global__ __launch_bounds__(256) void k_attn2(const float* __restrict__ ht,
                                               const unsigned short* __restrict__ Uhi,
                                               const unsigned short* __restrict__ Ulo,
                                               const unsigned short* __restrict__ VT,
                                               const float* __restrict__ pt,
                                               const int* __restrict__ meta,
                                               unsigned short* __restrict__ ctx) {
    __shared__ float sPart[4][32 * 48];
    __shared__ float sScore[32 * 48];
    __shared__ unsigned short sPhi[32 * 72];
    __shared__ unsigned short sPlo[32 * 72];

    const int tid = threadIdx.x;
    const int w = tid >> 6, lane = tid & 63;
    const int n = blockIdx.x >> 3, q0 = (blockIdx.x & 7) * 32;
    const int ls = meta[n], lc = meta[64 + n];
    const float p = pt[n];
    const int r16 = lane & 15, khalf = lane >> 4, rg = lane >> 4;

    const float* hbase = ht + ((size_t)(n * QQ + q0)) * HH;
    const unsigned short* uhbase = Uhi + (size_t)n * WROWS * HH;
    const unsigned short* ulbase = Ulo + (size_t)n * WROWS * HH;

    // ---- Phase A ----
    f32x4 acc[2][3] = {};
    for (int ks = 0; ks < 8; ++ks) {
        int kcol = w * 256 + ks * 32 + khalf * 8;
        short8 ah[2], al[2];
#pragma unroll
        for (int mf = 0; mf < 2; ++mf) {
            const float* src = hbase + (size_t)(mf * 16 + r16) * HH + kcol;
            f32x4 v0 = *(const f32x4*)src;
            f32x4 v1 = *(const f32x4*)(src + 4);
            float vv[8] = {v0[0], v0[1], v0[2], v0[3], v1[0], v1[1], v1[2], v1[3]};
#pragma unroll
            for (int j = 0; j < 8; ++j) {
                unsigned short hb = f2bf(vv[j]);
                ah[mf][j] = (short)hb;
                al[mf][j] = (short)f2bf(vv[j] - bf2f(hb));
            }
        }
#pragma unroll
        for (int nf = 0; nf < 3; ++nf) {
            size_t uoff = (size_t)(nf * 16 + r16) * HH + kcol;
            short8 bh = *(const short8*)(uhbase + uoff);
            short8 bl = *(const short8*)(ulbase + uoff);
#pragma unroll
            for (int mf = 0; mf < 2; ++mf) {
                acc[mf][nf] = __builtin_amdgcn_mfma_f32_16x16x32_bf16(ah[mf], bh, acc[mf][nf], 0, 0, 0);
                acc[mf][nf] = __builtin_amdgcn_mfma_f32_16x16x32_bf16(ah[mf], bl, acc[mf][nf], 0, 0, 0);
                acc[mf][nf] = __builtin_amdgcn_mfma_f32_16x16x32_bf16(al[mf], bh, acc[mf][nf], 0, 0, 0);
            }
        }
    }
#pragma unroll
    for (int mf = 0; mf < 2; ++mf)
#pragma unroll
        for (int nf = 0; nf < 3; ++nf)
#pragma unroll
            for (int r = 0; r < 4; ++r)
                sPart[w][(mf * 16 + rg * 4 + r) * 48 + nf * 16 + r16] = acc[mf][nf][r];
    __syncthreads();

    // ---- reduce + softmax + gauss ----
    {
        int q = tid >> 3, g = tid & 7;
        float sc6[6];
#pragma unroll
        for (int s = 0; s < 6; ++s) {
            int li = g + 8 * s;
            int o = q * 48 + li;
            sc6[s] = sPart[0][o] + sPart[1][o] + sPart[2][o] + sPart[3][o];
        }
        float mx = -1e30f;
#pragma unroll
        for (int s = 0; s < 6; ++s) { int li = g + 8 * s; if (li < lc) mx = fmaxf(mx, sc6[s]); }
        for (int off = 1; off < 8; off <<= 1) mx = fmaxf(mx, __shfl_xor(mx, off, 8));
        float sum = 0.f, ex[6];
#pragma unroll
        for (int s = 0; s < 6; ++s) {
            int li = g + 8 * s;
            float e = (li < lc) ? __expf(sc6[s] - mx) : 0.f;
            ex[s] = e; sum += e;
        }
        for (int off = 1; off < 8; off <<= 1) sum += __shfl_xor(sum, off, 8);
        float inv = 1.0f / sum;
#pragma unroll
        for (int s = 0; s < 6; ++s) {
            int li = g + 8 * s;
            float d = (float)(ls + li) - p;
            float gs = __expf(-(d * d) * (1.0f / 128.0f));
            sScore[q * 48 + li] = ex[s] * inv * gs;
        }
    }
    __syncthreads();

    {
        int row = tid >> 3, c0 = (tid & 7) * 8;
#pragma unroll
        for (int j = 0; j < 8; ++j) {
            int c = c0 + j;
            float pv = (c < 48) ? sScore[row * 48 + c] : 0.f;
            unsigned short hb = f2bf(pv);
            sPhi[row * 72 + c] = hb;
            sPlo[row * 72 + c] = f2bf(pv - bf2f(hb));
        }
    }
    __syncthreads();

    // ---- Phase B ----
    short8 pa[2][2], plq[2][2];
#pragma unroll
    for (int mf = 0; mf < 2; ++mf)
#pragma unroll
        for (int ks = 0; ks < 2; ++ks) {
            pa[mf][ks]  = *(const short8*)&sPhi[(mf * 16 + r16) * 72 + ks * 32 + khalf * 8];
            plq[mf][ks] = *(const short8*)&sPlo[(mf * 16 + r16) * 72 + ks * 32 + khalf * 8];
        }
    const unsigned short* vtb = VT + n * 64 + khalf * 8;
#pragma unroll
    for (int half = 0; half < 2; ++half) {
        f32x4 accB[2][8] = {};
        const int hcol0 = w * 256 + half * 128;
#pragma unroll
        for (int nf = 0; nf < 8; ++nf) {
            const int o = hcol0 + nf * 16 + r16;
#pragma unroll
            for (int ks = 0; ks < 2; ++ks) {
                short8 bfrag = *(const short8*)(vtb + (size_t)o * VTN + ks * 32);
#pragma unroll
                for (int mf = 0; mf < 2; ++mf) {
                    accB[mf][nf] = __builtin_amdgcn_mfma_f32_16x16x32_bf16(pa[mf][ks], bfrag, accB[mf][nf], 0, 0, 0);
                    accB[mf][nf] = __builtin_amdgcn_mfma_f32_16x16x32_bf16(plq[mf][ks], bfrag, accB[mf][nf], 0, 0, 0);
                }
            }
        }
#pragma unroll
        for (int mf = 0; mf < 2; ++mf)
#pragma unroll
            for (int nf = 0; nf < 8; ++nf)
#pragma unroll
                for (int r = 0; r < 4; ++r)
                    ctx[(size_t)(n * QQ + q0 + mf * 16 + rg * 4 + r) * HH + hcol0 + nf * 16 + r16] =
                        f2bf(accB[mf][nf][r]);
    }
}

// ---------------- K6: out = tanh(h @ Wc2^T + out_ctx), counted-vmcnt pipeline ----------------
// Stage order per K-tile batch: [A0,A0,B0,B0,A1,A1,B1,B1] (2 loads per half-tile).
// Steady state: vmcnt(8) after P1 MFMA (completes A1,B1 of tile t: used P2/P3),
//               vmcnt(4) after P4 MFMA (completes A0,B0 of tile t+1: used next P1).
#define RD_A(dst, buf, mh, mq, ksub) \
    dst = *(const short8*)&sA[(buf) * 16384 + (mh) * 8192 + \
        (wr * 64 + (mq) * 16 + r16) * 64 + ((((ksub) * 4 + kg) ^ (r16 & 7)) * 8)];
#define RD_B(dst, buf, nh, nq, ksub) \
    dst = *(const short8*)&sB[(buf) * 16384 + (nh) * 8192 + \
        (wc * 32 + (nq) * 16 + r16) * 64 + ((((ksub) * 4 + kg) ^ (r16 & 7)) * 8)];
#define MFMA_QUAD(MH, NH) \
    _Pragma("unroll") \
    for (int mq = 0; mq < 4; ++mq) { \
        _Pragma("unroll") \
        for (int nq = 0; nq < 2; ++nq) { \
            f32x4 c = acc[(MH) * 4 + mq][(NH) * 2 + nq]; \
            c = __builtin_amdgcn_mfma_f32_16x16x32_bf16(a[mq][0], b[nq][0], c, 0, 0, 0); \
            c = __builtin_amdgcn_mfma_f32_16x16x32_bf16(a[mq][1], b[nq][1], c, 0, 0, 0); \
            acc[(MH) * 4 + mq][(NH) * 2 + nq] = c; \
        } \
    }
#define PHASE_SYNC() \
    __builtin_amdgcn_s_barrier(); \
    asm volatile("s_waitcnt lgkmcnt(0)" ::: "memory"); \
    __builtin_amdgcn_sched_barrier(0);

__global__ __launch_bounds__(512, 1) void k_out_gemm256(
    const unsigned short* __restrict__ Ahf,
    const unsigned short* __restrict__ Bt,
    const unsigned short* __restrict__ Cadd,
    float* __restrict__ out) {
    extern __shared__ unsigned short lds[];
    unsigned short* sA = lds;          // [2 buf][2 half][128*64]
    unsigned short* sB = lds + 32768;

    const int tid = threadIdx.x;
    const int wid = tid >> 6, lane = tid & 63;
    const int bid = blockIdx.x;
    const int swz = (bid & 7) * 32 + (bid >> 3);
    const int mt = swz >> 2, ntile = swz & 3;
    const int m0 = mt * 256, n0 = ntile * 256;
    const int wr = wid >> 2, wc = wid & 3;
    const int r16 = lane & 15, kg = lane >> 4;

    const int srow = lane >> 3;
    const int kswz = ((lane & 7) ^ srow) * 8;

    f32x4 acc[8][4] = {};

    auto stage_tile = [&](int buf, int kb) {
#pragma unroll
        for (int half = 0; half < 2; ++half) {
#pragma unroll
            for (int i = 0; i < 2; ++i) {
                int r = half * 128 + i * 64 + wid * 8 + srow;
                lds_load16(Ahf + (size_t)(m0 + r) * HH + kb + kswz,
                           sA + buf * 16384 + half * 8192 + i * 4096 + wid * 512);
            }
#pragma unroll
            for (int i = 0; i < 2; ++i) {
                int r = half * 128 + i * 64 + wid * 8 + srow;
                lds_load16(Bt + (size_t)(n0 + r) * (2 * HH) + 1024 + kb + kswz,
                           sB + buf * 16384 + half * 8192 + i * 4096 + wid * 512);
            }
        }
    };

    stage_tile(0, 0);
    asm volatile("s_waitcnt vmcnt(4)" ::: "memory");   // A0,B0 of tile 0 landed
    __builtin_amdgcn_s_barrier();

    short8 a[4][2], b[2][2];
    for (int t = 0; t < 16; ++t) {
        const int buf = t & 1;
        // ---- P1 (mh0, nh0): reads A0,B0 of tile t; stages tile t+1 ----
#pragma unroll
        for (int mq = 0; mq < 4; ++mq) { RD_A(a[mq][0], buf, 0, mq, 0) RD_A(a[mq][1], buf, 0, mq, 1) }
#pragma unroll
        for (int nq = 0; nq < 2; ++nq) { RD_B(b[nq][0], buf, 0, nq, 0) RD_B(b[nq][1], buf, 0, nq, 1) }
        if (t + 1 < 16) stage_tile(buf ^ 1, (t + 1) * 64);
        PHASE_SYNC()
        __builtin_amdgcn_s_setprio(1);
        MFMA_QUAD(0, 0)
        __builtin_amdgcn_s_setprio(0);
        if (t + 1 < 16) { asm volatile("s_waitcnt vmcnt(8)" ::: "memory"); }
        else            { asm volatile("s_waitcnt vmcnt(0)" ::: "memory"); }
        __builtin_amdgcn_s_barrier();
        // ---- P2 (mh0, nh1): reads B1 of tile t (just completed) ----
#pragma unroll
        for (int nq = 0; nq < 2; ++nq) { RD_B(b[nq][0], buf, 1, nq, 0) RD_B(b[nq][1], buf, 1, nq, 1) }
        PHASE_SYNC()
        __builtin_amdgcn_s_setprio(1);
        MFMA_QUAD(0, 1)
        __builtin_amdgcn_s_setprio(0);
        __builtin_amdgcn_s_barrier();
        // ---- P3 (mh1, nh1): reads A1 of tile t ----
#pragma unroll
        for (int mq = 0; mq < 4; ++mq) { RD_A(a[mq][0], buf, 1, mq, 0) RD_A(a[mq][1], buf, 1, mq, 1) }
        PHASE_SYNC()
        __builtin_amdgcn_s_setprio(1);
        MFMA_QUAD(1, 1)
        __builtin_amdgcn_s_setprio(0);
        __builtin_amdgcn_s_barrier();
        // ---- P4 (mh1, nh0): reads B0 again; completes A0,B0 of tile t+1 ----
#pragma unroll
        for (int nq = 0; nq < 2; ++nq) { RD_B(b[nq][0], buf, 0, nq, 0) RD_B(b[nq][1], buf, 0, nq, 1) }
        PHASE_SYNC()
        __builtin_amdgcn_s_setprio(1);
        MFMA_QUAD(1, 0)
        __builtin_amdgcn_s_setprio(0);
        asm volatile("s_waitcnt vmcnt(4)" ::: "memory");
        __builtin_amdgcn_s_barrier();
    }

#pragma unroll
    for (int m = 0; m < 8; ++m)
#pragma unroll
        for (int n = 0; n < 4; ++n) {
            int row = m0 + (m >> 2) * 128 + wr * 64 + (m & 3) * 16 + kg * 4;
            int col = n0 + (n >> 1) * 128 + wc * 32 + (n & 1) * 16 + r16;
#pragma unroll
            for (int r = 0; r < 4; ++r) {
                float cadd = bf2f(Cadd[(size_t)(row + r) * HH + col]);
                out[(size_t)(row + r) * HH + col] = fast_tanh(acc[m][n][r] + cadd);
            }
        }
}

extern "C" void kernel_launch(void* const* d_in, const int* in_sizes, int n_in,
                              void* d_out, int out_size, void* d_ws, size_t ws_size,
                              hipStream_t stream) {
    const float* enc  = (const float*)d_in[0];
    const float* ht   = (const float*)d_in[1];
    const int*   slen = (const int*)d_in[2];
    const float* pt   = (const float*)d_in[3];
    const float* Wa   = (const float*)d_in[4];
    const float* Wc   = (const float*)d_in[5];
    float* out = (float*)d_out;

    char* ws = (char*)d_ws;
    int* meta = (int*)(ws + OFF_META);
    unsigned short* wehi = (unsigned short*)(ws + OFF_WEHI);
    unsigned short* welo = (unsigned short*)(ws + OFF_WELO);
    unsigned short* wahi = (unsigned short*)(ws + OFF_WAHI);
    unsigned short* walo = (unsigned short*)(ws + OFF_WALO);
    unsigned short* wcbf = (unsigned short*)(ws + OFF_WCBF);
    unsigned short* hbf  = (unsigned short*)(ws + OFF_HBF);
    unsigned short* uhi  = (unsigned short*)(ws + OFF_UHI);
    unsigned short* ulo  = (unsigned short*)(ws + OFF_ULO);
    unsigned short* ctx  = (unsigned short*)(ws + OFF_CTX);
    unsigned short* vt   = (unsigned short*)(ws + OFF_VT);

    hipFuncSetAttribute((const void*)k_out_gemm256,
                        hipFuncAttributeMaxDynamicSharedMemorySize, 131072);

    hipLaunchKernelGGL(k_window, dim3(1), dim3(64), 0, stream, pt, slen, meta);
    hipLaunchKernelGGL(k_split, dim3((HH * HH / 4) / 256), dim3(256), 0, stream,
                       Wa, wahi, walo, HH * HH / 4);
    hipLaunchKernelGGL(k_tobf, dim3((HH * 2 * HH / 4) / 256), dim3(256), 0, stream,
                       Wc, wcbf, HH * 2 * HH / 4);
    hipLaunchKernelGGL(k_tobf, dim3((NB * QQ * HH / 4) / 256), dim3(256), 0, stream,
                       ht, hbf, NB * QQ * HH / 4);
    hipLaunchKernelGGL(k_gather, dim3(MU), dim3(256), 0, stream, enc, meta, wehi, welo);
    hipLaunchKernelGGL(k_ugemm64, dim3(HH / 64, MU / 64), dim3(256), 0, stream,
                       wehi, welo, wahi, walo, uhi, ulo);
    hipLaunchKernelGGL(k_vgemm64, dim3(MU / 64, HH / 64), dim3(256), 0, stream,
                       wcbf, wehi, welo, vt);
    hipLaunchKernelGGL(k_attn2, dim3(NB * 8), dim3(256), 0, stream,
                       ht, uhi, ulo, vt, pt, meta, ctx);
    hipLaunchKernelGGL(k_out_gemm256, dim3(256), dim3(512), 131072, stream,
                       hbf, wcbf, ctx, out);
}

// Round 6
// 158.406 us; speedup vs baseline: 2.0948x; 1.0752x over previous
//
#include <hip/hip_runtime.h>
#include <hip/hip_bf16.h>
#include <cstdint>

#define DEVINL __device__ __forceinline__

typedef __attribute__((ext_vector_type(8))) short short8;   // 8 bf16 in 4 VGPRs
typedef __attribute__((ext_vector_type(4))) float f32x4;
typedef __attribute__((ext_vector_type(4))) unsigned short u16x4;

static constexpr int NB = 64, LL = 258, HH = 1024, QQ = 256;
static constexpr int WROWS = 33;          // max window length (2*16+1)
static constexpr int MU = 2176;           // 64*33 = 2112 padded to 17*128
static constexpr int VTN = 4096;          // VT col stride: 64 n * 64 li

// ---- workspace layout (bytes) ----
static constexpr size_t OFF_META = 0;
static constexpr size_t SZ_WE   = (size_t)MU * HH * 2;
static constexpr size_t OFF_WEHI = 1024;
static constexpr size_t OFF_WELO = OFF_WEHI + SZ_WE;
static constexpr size_t OFF_WAHI = OFF_WELO + SZ_WE;
static constexpr size_t OFF_WALO = OFF_WAHI + (size_t)HH * HH * 2;
static constexpr size_t OFF_WCBF = OFF_WALO + (size_t)HH * HH * 2;
static constexpr size_t OFF_HBF  = OFF_WCBF + (size_t)HH * 2 * HH * 2;
static constexpr size_t OFF_U    = OFF_HBF + (size_t)NB * QQ * HH * 2;
static constexpr size_t OFF_UHI  = OFF_U;
static constexpr size_t OFF_ULO  = OFF_U + (size_t)MU * HH * 2;
static constexpr size_t OFF_CTX  = OFF_U + (size_t)MU * HH * 4;         // ctxP bf16, fragment-major
static constexpr size_t OFF_VT   = OFF_CTX + (size_t)NB * QQ * HH * 2;  // VT bf16 [1024][4096]

DEVINL unsigned short f2bf(float x) {
    union { float f; uint32_t u; } v; v.f = x;
    uint32_t u = v.u;
    uint32_t r = (u + 0x7FFFu + ((u >> 16) & 1u)) >> 16;
    return (unsigned short)r;
}
DEVINL float bf2f(unsigned short b) {
    union { uint32_t u; float f; } v; v.u = ((uint32_t)b) << 16;
    return v.f;
}

template <typename T>
DEVINL void lds_load16(const T* g, T* l) {
    __builtin_amdgcn_global_load_lds(
        (const __attribute__((address_space(1))) void*)g,
        (__attribute__((address_space(3))) void*)l, 16, 0, 0);
}

DEVINL float fast_tanh(float x) {
    float e = __expf(2.0f * x);
    return 1.0f - 2.0f / (e + 1.0f);
}

// window bounds from pt/slen (shared by k_prep gather + k_attn2)
DEVINL void window_of(float p, int sl, int& ls, int& lc) {
    float se = (float)sl;
    float s = fmaxf(p - 16.0f, 0.0f);
    float e = fminf(p + 16.0f, se);
    ls = (int)ceilf(s);
    int le = (int)floorf(e); if (le > LL - 1) le = LL - 1;
    lc = le - ls + 1;
    if (lc < 0) lc = 0;
    if (lc > WROWS) lc = WROWS;
}

// ---------------- K_prep: merged gather / Wa-split / Wc-bf / ht-bf ----------------
// blocks: [0,2176) gather windowed enc hi/lo; [2176,3200) Wa split;
//         [3200,5248) Wc tobf; [5248,21632) ht tobf.
__global__ __launch_bounds__(256) void k_prep(const float* __restrict__ enc,
                                              const float* __restrict__ ht,
                                              const float* __restrict__ pt,
                                              const int* __restrict__ slen,
                                              const float* __restrict__ Wa,
                                              const float* __restrict__ Wc,
                                              unsigned short* __restrict__ wehi,
                                              unsigned short* __restrict__ welo,
                                              unsigned short* __restrict__ wahi,
                                              unsigned short* __restrict__ walo,
                                              unsigned short* __restrict__ wcbf,
                                              unsigned short* __restrict__ hbf) {
    const int b = blockIdx.x, t = threadIdx.x;
    if (b < MU) {
        // gather windowed enc rows -> bf16 hi/lo, zero-pad
        int r = b;
        const float* src = nullptr;
        bool valid = false;
        if (r < NB * WROWS) {
            int n = r / WROWS, li = r - n * WROWS;
            int ls, lc;
            window_of(pt[n], slen[n], ls, lc);
            if (li < lc) { valid = true; src = enc + ((size_t)n * LL + ls + li) * HH; }
        }
        f32x4 v;
        if (valid) v = ((const f32x4*)src)[t];
        else { v[0] = 0.f; v[1] = 0.f; v[2] = 0.f; v[3] = 0.f; }
        u16x4 h, l;
#pragma unroll
        for (int j = 0; j < 4; ++j) {
            unsigned short hb = f2bf(v[j]);
            h[j] = hb;
            l[j] = f2bf(v[j] - bf2f(hb));
        }
        size_t o = (size_t)r * HH / 4 + t;
        ((u16x4*)wehi)[o] = h;
        ((u16x4*)welo)[o] = l;
    } else if (b < MU + 1024) {
        // Wa f32 -> hi/lo
        int i = (b - MU) * 256 + t;            // < 262144
        f32x4 v = ((const f32x4*)Wa)[i];
        u16x4 h, l;
#pragma unroll
        for (int j = 0; j < 4; ++j) {
            unsigned short hb = f2bf(v[j]);
            h[j] = hb;
            l[j] = f2bf(v[j] - bf2f(hb));
        }
        ((u16x4*)wahi)[i] = h;
        ((u16x4*)walo)[i] = l;
    } else if (b < MU + 1024 + 2048) {
        // Wc f32 -> bf16
        int i = (b - MU - 1024) * 256 + t;     // < 524288
        f32x4 v = ((const f32x4*)Wc)[i];
        u16x4 h;
#pragma unroll
        for (int j = 0; j < 4; ++j) h[j] = f2bf(v[j]);
        ((u16x4*)wcbf)[i] = h;
    } else {
        // ht f32 -> bf16
        int i = (b - MU - 3072) * 256 + t;     // < 4194304
        f32x4 v = ((const f32x4*)ht)[i];
        u16x4 h;
#pragma unroll
        for (int j = 0; j < 4; ++j) h[j] = f2bf(v[j]);
        ((u16x4*)hbf)[i] = h;
    }
}

// ---------------- K4: U = we @ W_a^T  (64x64 tile, dbuf 2-phase, 3-term) ----------------
__global__ __launch_bounds__(256) void k_ugemm64(const unsigned short* __restrict__ Ahi,
                                                 const unsigned short* __restrict__ Alo,
                                                 const unsigned short* __restrict__ Bhi,
                                                 const unsigned short* __restrict__ Blo,
                                                 unsigned short* __restrict__ Uhi,
                                                 unsigned short* __restrict__ Ulo) {
    __shared__ unsigned short sAh[2][64 * 32], sAl[2][64 * 32], sBh[2][64 * 32], sBl[2][64 * 32];
    const int tid = threadIdx.x;
    const int w = tid >> 6, lane = tid & 63;
    const int m0 = blockIdx.y * 64, n0 = blockIdx.x * 64;
    const int wr = w >> 1, wc = w & 1;
    const int r16 = lane & 15, khalf = lane >> 4;
    const int srow = tid >> 2;
    const int scol = ((tid & 3) ^ ((tid >> 3) & 3)) * 8;
    const int ldso = tid * 8;
    const int kslot = (khalf ^ ((r16 >> 1) & 3)) * 8;
    f32x4 acc[2][2] = {};

    auto stage = [&](int buf, int kb) {
        lds_load16(Ahi + (size_t)(m0 + srow) * HH + kb + scol, &sAh[buf][ldso]);
        lds_load16(Alo + (size_t)(m0 + srow) * HH + kb + scol, &sAl[buf][ldso]);
        lds_load16(Bhi + (size_t)(n0 + srow) * HH + kb + scol, &sBh[buf][ldso]);
        lds_load16(Blo + (size_t)(n0 + srow) * HH + kb + scol, &sBl[buf][ldso]);
    };

    stage(0, 0);
    for (int t = 0; t < 32; ++t) {
        const int buf = t & 1;
        asm volatile("s_waitcnt vmcnt(0)" ::: "memory");
        __builtin_amdgcn_s_barrier();
        short8 ah[2], al[2], bh[2], bl[2];
#pragma unroll
        for (int f = 0; f < 2; ++f) {
            int ai = (wr * 32 + f * 16 + r16) * 32 + kslot;
            ah[f] = *(const short8*)&sAh[buf][ai];
            al[f] = *(const short8*)&sAl[buf][ai];
            int bi = (wc * 32 + f * 16 + r16) * 32 + kslot;
            bh[f] = *(const short8*)&sBh[buf][bi];
            bl[f] = *(const short8*)&sBl[buf][bi];
        }
        if (t + 1 < 32) stage(buf ^ 1, (t + 1) * 32);
        asm volatile("s_waitcnt lgkmcnt(0)" ::: "memory");
        __builtin_amdgcn_sched_barrier(0);
#pragma unroll
        for (int mf = 0; mf < 2; ++mf)
#pragma unroll
            for (int nf = 0; nf < 2; ++nf) {
                acc[mf][nf] = __builtin_amdgcn_mfma_f32_16x16x32_bf16(ah[mf], bh[nf], acc[mf][nf], 0, 0, 0);
                acc[mf][nf] = __builtin_amdgcn_mfma_f32_16x16x32_bf16(ah[mf], bl[nf], acc[mf][nf], 0, 0, 0);
                acc[mf][nf] = __builtin_amdgcn_mfma_f32_16x16x32_bf16(al[mf], bh[nf], acc[mf][nf], 0, 0, 0);
            }
        __builtin_amdgcn_s_barrier();
    }
    const int rg = lane >> 4;
#pragma unroll
    for (int mf = 0; mf < 2; ++mf)
#pragma unroll
        for (int nf = 0; nf < 2; ++nf)
#pragma unroll
            for (int r = 0; r < 4; ++r) {
                int m = m0 + wr * 32 + mf * 16 + rg * 4 + r;
                int nn = n0 + wc * 32 + nf * 16 + r16;
                float v = acc[mf][nf][r];
                unsigned short h = f2bf(v);
                Uhi[(size_t)m * HH + nn] = h;
                Ulo[(size_t)m * HH + nn] = f2bf(v - bf2f(h));
            }
}

// ---------------- K4b: VT = Wc1 @ we^T  (64x64 tile, dbuf 2-phase, 2-term) ----------------
__global__ __launch_bounds__(256) void k_vgemm64(const unsigned short* __restrict__ Wc1,
                                                 const unsigned short* __restrict__ Bhi,
                                                 const unsigned short* __restrict__ Blo,
                                                 unsigned short* __restrict__ VT) {
    __shared__ unsigned short sA[2][64 * 32], sBh[2][64 * 32], sBl[2][64 * 32];
    const int tid = threadIdx.x;
    const int w = tid >> 6, lane = tid & 63;
    const int m0 = blockIdx.y * 64, n0 = blockIdx.x * 64;
    const int wr = w >> 1, wc = w & 1;
    const int r16 = lane & 15, khalf = lane >> 4;
    const int srow = tid >> 2;
    const int scol = ((tid & 3) ^ ((tid >> 3) & 3)) * 8;
    const int ldso = tid * 8;
    const int kslot = (khalf ^ ((r16 >> 1) & 3)) * 8;
    f32x4 acc[2][2] = {};

    auto stage = [&](int buf, int kb) {
        lds_load16(Wc1 + (size_t)(m0 + srow) * (2 * HH) + kb + scol, &sA[buf][ldso]);
        lds_load16(Bhi + (size_t)(n0 + srow) * HH + kb + scol, &sBh[buf][ldso]);
        lds_load16(Blo + (size_t)(n0 + srow) * HH + kb + scol, &sBl[buf][ldso]);
    };

    stage(0, 0);
    for (int t = 0; t < 32; ++t) {
        const int buf = t & 1;
        asm volatile("s_waitcnt vmcnt(0)" ::: "memory");
        __builtin_amdgcn_s_barrier();
        short8 af[2], bh[2], bl[2];
#pragma unroll
        for (int f = 0; f < 2; ++f) {
            af[f] = *(const short8*)&sA[buf][(wr * 32 + f * 16 + r16) * 32 + kslot];
            int bi = (wc * 32 + f * 16 + r16) * 32 + kslot;
            bh[f] = *(const short8*)&sBh[buf][bi];
            bl[f] = *(const short8*)&sBl[buf][bi];
        }
        if (t + 1 < 32) stage(buf ^ 1, (t + 1) * 32);
        asm volatile("s_waitcnt lgkmcnt(0)" ::: "memory");
        __builtin_amdgcn_sched_barrier(0);
#pragma unroll
        for (int mf = 0; mf < 2; ++mf)
#pragma unroll
            for (int nf = 0; nf < 2; ++nf) {
                acc[mf][nf] = __builtin_amdgcn_mfma_f32_16x16x32_bf16(af[mf], bh[nf], acc[mf][nf], 0, 0, 0);
                acc[mf][nf] = __builtin_amdgcn_mfma_f32_16x16x32_bf16(af[mf], bl[nf], acc[mf][nf], 0, 0, 0);
            }
        __builtin_amdgcn_s_barrier();
    }
    const int rg = lane >> 4;
#pragma unroll
    for (int mf = 0; mf < 2; ++mf)
#pragma unroll
        for (int nf = 0; nf < 2; ++nf)
#pragma unroll
            for (int r = 0; r < 4; ++r) {
                int o = m0 + wr * 32 + mf * 16 + rg * 4 + r;
                int wrow = n0 + wc * 32 + nf * 16 + r16;
                int n = wrow / WROWS, li = wrow - n * WROWS;
                if (n < NB)
                    VT[(size_t)o * VTN + n * 64 + li] = f2bf(acc[mf][nf][r]);
            }
}

// ---------------- K5: fused attention: score + softmax + gauss + P@VT -> ctxP ----------------
// ctxP layout is fragment-major, keyed to k_out_gemm256's ownership:
//   element (rowT,colT) of out-tile (tm,tn): m=(rowT>>7)*4+((rowT>>4)&3), half=colT>>7,
//   ib=m*2+half, iw=((colT>>4)&1)*4+(rowT&3), tid=((rowT>>6)&1)*256+((colT>>5)&3)*64+lane
//   addr = (((tm*4+tn)*16+ib)*512+tid)*8+iw.  Both producer stores and consumer loads
//   are 16B/lane, wave-contiguous.
__global__ __launch_bounds__(256) void k_attn2(const float* __restrict__ ht,
                                               const unsigned short* __restrict__ Uhi,
                                               const unsigned short* __restrict__ Ulo,
                                               const unsigned short* __restrict__ VT,
                                               const float* __restrict__ pt,
                                               const int* __restrict__ slen,
                                               unsigned short* __restrict__ ctxP) {
    __shared__ float sPart[4][32 * 48];
    __shared__ float sScore[32 * 48];
    __shared__ unsigned short sPhi[32 * 72];
    __shared__ unsigned short sPlo[32 * 72];

    const int tid = threadIdx.x;
    const int w = tid >> 6, lane = tid & 63;
    const int n = blockIdx.x >> 3, q0 = (blockIdx.x & 7) * 32;
    int ls, lc;
    window_of(pt[n], slen[n], ls, lc);
    const float p = pt[n];
    const int r16 = lane & 15, khalf = lane >> 4, rg = lane >> 4;

    const float* hbase = ht + ((size_t)(n * QQ + q0)) * HH;
    const unsigned short* uhbase = Uhi + (size_t)n * WROWS * HH;
    const unsigned short* ulbase = Ulo + (size_t)n * WROWS * HH;

    // ---- Phase A ----
    f32x4 acc[2][3] = {};
    for (int ks = 0; ks < 8; ++ks) {
        int kcol = w * 256 + ks * 32 + khalf * 8;
        short8 ah[2], al[2];
#pragma unroll
        for (int mf = 0; mf < 2; ++mf) {
            const float* src = hbase + (size_t)(mf * 16 + r16) * HH + kcol;
            f32x4 v0 = *(const f32x4*)src;
            f32x4 v1 = *(const f32x4*)(src + 4);
            float vv[8] = {v0[0], v0[1], v0[2], v0[3], v1[0], v1[1], v1[2], v1[3]};
#pragma unroll
            for (int j = 0; j < 8; ++j) {
                unsigned short hb = f2bf(vv[j]);
                ah[mf][j] = (short)hb;
                al[mf][j] = (short)f2bf(vv[j] - bf2f(hb));
            }
        }
#pragma unroll
        for (int nf = 0; nf < 3; ++nf) {
            size_t uoff = (size_t)(nf * 16 + r16) * HH + kcol;
            short8 bh = *(const short8*)(uhbase + uoff);
            short8 bl = *(const short8*)(ulbase + uoff);
#pragma unroll
            for (int mf = 0; mf < 2; ++mf) {
                acc[mf][nf] = __builtin_amdgcn_mfma_f32_16x16x32_bf16(ah[mf], bh, acc[mf][nf], 0, 0, 0);
                acc[mf][nf] = __builtin_amdgcn_mfma_f32_16x16x32_bf16(ah[mf], bl, acc[mf][nf], 0, 0, 0);
                acc[mf][nf] = __builtin_amdgcn_mfma_f32_16x16x32_bf16(al[mf], bh, acc[mf][nf], 0, 0, 0);
            }
        }
    }
#pragma unroll
    for (int mf = 0; mf < 2; ++mf)
#pragma unroll
        for (int nf = 0; nf < 3; ++nf)
#pragma unroll
            for (int r = 0; r < 4; ++r)
                sPart[w][(mf * 16 + rg * 4 + r) * 48 + nf * 16 + r16] = acc[mf][nf][r];
    __syncthreads();

    // ---- reduce + softmax + gauss ----
    {
        int q = tid >> 3, g = tid & 7;
        float sc6[6];
#pragma unroll
        for (int s = 0; s < 6; ++s) {
            int li = g + 8 * s;
            int o = q * 48 + li;
            sc6[s] = sPart[0][o] + sPart[1][o] + sPart[2][o] + sPart[3][o];
        }
        float mx = -1e30f;
#pragma unroll
        for (int s = 0; s < 6; ++s) { int li = g + 8 * s; if (li < lc) mx = fmaxf(mx, sc6[s]); }
        for (int off = 1; off < 8; off <<= 1) mx = fmaxf(mx, __shfl_xor(mx, off, 8));
        float sum = 0.f, ex[6];
#pragma unroll
        for (int s = 0; s < 6; ++s) {
            int li = g + 8 * s;
            float e = (li < lc) ? __expf(sc6[s] - mx) : 0.f;
            ex[s] = e; sum += e;
        }
        for (int off = 1; off < 8; off <<= 1) sum += __shfl_xor(sum, off, 8);
        float inv = 1.0f / sum;
#pragma unroll
        for (int s = 0; s < 6; ++s) {
            int li = g + 8 * s;
            float d = (float)(ls + li) - p;
            float gs = __expf(-(d * d) * (1.0f / 128.0f));
            sScore[q * 48 + li] = ex[s] * inv * gs;
        }
    }
    __syncthreads();

    {
        int row = tid >> 3, c0 = (tid & 7) * 8;
#pragma unroll
        for (int j = 0; j < 8; ++j) {
            int c = c0 + j;
            float pv = (c < 48) ? sScore[row * 48 + c] : 0.f;
            unsigned short hb = f2bf(pv);
            sPhi[row * 72 + c] = hb;
            sPlo[row * 72 + c] = f2bf(pv - bf2f(hb));
        }
    }
    __syncthreads();

    // ---- Phase B: P @ VT, store fragment-major ctxP ----
    short8 pa[2][2], plq[2][2];
#pragma unroll
    for (int mf = 0; mf < 2; ++mf)
#pragma unroll
        for (int ks = 0; ks < 2; ++ks) {
            pa[mf][ks]  = *(const short8*)&sPhi[(mf * 16 + r16) * 72 + ks * 32 + khalf * 8];
            plq[mf][ks] = *(const short8*)&sPlo[(mf * 16 + r16) * 72 + ks * 32 + khalf * 8];
        }
    const unsigned short* vtb = VT + n * 64 + khalf * 8;
    const size_t tile16 = (size_t)(n * 4 + w) * 16;
#pragma unroll
    for (int half = 0; half < 2; ++half) {
        f32x4 accB[2][8] = {};
        const int hcol0 = w * 256 + half * 128;
#pragma unroll
        for (int nf = 0; nf < 8; ++nf) {
            const int o = hcol0 + nf * 16 + r16;
#pragma unroll
            for (int ks = 0; ks < 2; ++ks) {
                short8 bfrag = *(const short8*)(vtb + (size_t)o * VTN + ks * 32);
#pragma unroll
                for (int mf = 0; mf < 2; ++mf) {
                    accB[mf][nf] = __builtin_amdgcn_mfma_f32_16x16x32_bf16(pa[mf][ks], bfrag, accB[mf][nf], 0, 0, 0);
                    accB[mf][nf] = __builtin_amdgcn_mfma_f32_16x16x32_bf16(plq[mf][ks], bfrag, accB[mf][nf], 0, 0, 0);
                }
            }
        }
        // packed coalesced store: 16B per lane per (mf,nfp)
#pragma unroll
        for (int mf = 0; mf < 2; ++mf) {
            const int br = q0 + mf * 16;                       // base row in tile (lane-uniform)
            const int m  = (br >> 7) * 4 + ((br >> 4) & 3);
            const int wr2 = (br >> 6) & 1;
            const int ib = m * 2 + half;
#pragma unroll
            for (int nfp = 0; nfp < 4; ++nfp) {
                short8 pk;
#pragma unroll
                for (int r = 0; r < 4; ++r) {
                    pk[r]     = (short)f2bf(accB[mf][2 * nfp][r]);
                    pk[4 + r] = (short)f2bf(accB[mf][2 * nfp + 1][r]);
                }
                const int tid_o = wr2 * 256 + nfp * 64 + lane;
                size_t off = (((tile16 + ib) * 512) + tid_o) * 8;
                *(short8*)&ctxP[off] = pk;
            }
        }
    }
}

// ---------------- K6: out = tanh(h @ Wc2^T + ctxP), 256^2 8-phase ----------------
#define RD_A(dst, buf, mh, mq, ksub) \
    dst = *(const short8*)&sA[(buf) * 16384 + (mh) * 8192 + \
        (wr * 64 + (mq) * 16 + r16) * 64 + ((((ksub) * 4 + kg) ^ (r16 & 7)) * 8)];
#define RD_B(dst, buf, nh, nq, ksub) \
    dst = *(const short8*)&sB[(buf) * 16384 + (nh) * 8192 + \
        (wc * 32 + (nq) * 16 + r16) * 64 + ((((ksub) * 4 + kg) ^ (r16 & 7)) * 8)];
#define MFMA_QUAD(MH, NH) \
    _Pragma("unroll") \
    for (int mq = 0; mq < 4; ++mq) { \
        _Pragma("unroll") \
        for (int nq = 0; nq < 2; ++nq) { \
            f32x4 c = acc[(MH) * 4 + mq][(NH) * 2 + nq]; \
            c = __builtin_amdgcn_mfma_f32_16x16x32_bf16(a[mq][0], b[nq][0], c, 0, 0, 0); \
            c = __builtin_amdgcn_mfma_f32_16x16x32_bf16(a[mq][1], b[nq][1], c, 0, 0, 0); \
            acc[(MH) * 4 + mq][(NH) * 2 + nq] = c; \
        } \
    }
#define PHASE_SYNC() \
    __builtin_amdgcn_s_barrier(); \
    asm volatile("s_waitcnt lgkmcnt(0)" ::: "memory"); \
    __builtin_amdgcn_sched_barrier(0);

__global__ __launch_bounds__(512, 1) void k_out_gemm256(
    const unsigned short* __restrict__ Ahf,
    const unsigned short* __restrict__ Bt,
    const unsigned short* __restrict__ Cp,
    float* __restrict__ out) {
    extern __shared__ unsigned short lds[];
    unsigned short* sA = lds;          // [2 buf][2 half][128*64]
    unsigned short* sB = lds + 32768;

    const int tid = threadIdx.x;
    const int wid = tid >> 6, lane = tid & 63;
    const int bid = blockIdx.x;
    const int swz = (bid & 7) * 32 + (bid >> 3);
    const int mt = swz >> 2, ntile = swz & 3;
    const int m0 = mt * 256, n0 = ntile * 256;
    const int wr = wid >> 2, wc = wid & 3;
    const int r16 = lane & 15, kg = lane >> 4;

    const int srow = lane >> 3;
    const int kswz = ((lane & 7) ^ srow) * 8;

    f32x4 acc[8][4] = {};

    auto stage_tile = [&](int buf, int kb) {
#pragma unroll
        for (int half = 0; half < 2; ++half) {
#pragma unroll
            for (int i = 0; i < 2; ++i) {
                int r = half * 128 + i * 64 + wid * 8 + srow;
                lds_load16(Ahf + (size_t)(m0 + r) * HH + kb + kswz,
                           sA + buf * 16384 + half * 8192 + i * 4096 + wid * 512);
            }
#pragma unroll
            for (int i = 0; i < 2; ++i) {
                int r = half * 128 + i * 64 + wid * 8 + srow;
                lds_load16(Bt + (size_t)(n0 + r) * (2 * HH) + 1024 + kb + kswz,
                           sB + buf * 16384 + half * 8192 + i * 4096 + wid * 512);
            }
        }
    };

    stage_tile(0, 0);
    asm volatile("s_waitcnt vmcnt(4)" ::: "memory");
    __builtin_amdgcn_s_barrier();

    short8 a[4][2], b[2][2];
    for (int t = 0; t < 16; ++t) {
        const int buf = t & 1;
#pragma unroll
        for (int mq = 0; mq < 4; ++mq) { RD_A(a[mq][0], buf, 0, mq, 0) RD_A(a[mq][1], buf, 0, mq, 1) }
#pragma unroll
        for (int nq = 0; nq < 2; ++nq) { RD_B(b[nq][0], buf, 0, nq, 0) RD_B(b[nq][1], buf, 0, nq, 1) }
        if (t + 1 < 16) stage_tile(buf ^ 1, (t + 1) * 64);
        PHASE_SYNC()
        __builtin_amdgcn_s_setprio(1);
        MFMA_QUAD(0, 0)
        __builtin_amdgcn_s_setprio(0);
        if (t + 1 < 16) { asm volatile("s_waitcnt vmcnt(8)" ::: "memory"); }
        else            { asm volatile("s_waitcnt vmcnt(0)" ::: "memory"); }
        __builtin_amdgcn_s_barrier();
#pragma unroll
        for (int nq = 0; nq < 2; ++nq) { RD_B(b[nq][0], buf, 1, nq, 0) RD_B(b[nq][1], buf, 1, nq, 1) }
        PHASE_SYNC()
        __builtin_amdgcn_s_setprio(1);
        MFMA_QUAD(0, 1)
        __builtin_amdgcn_s_setprio(0);
        __builtin_amdgcn_s_barrier();
#pragma unroll
        for (int mq = 0; mq < 4; ++mq) { RD_A(a[mq][0], buf, 1, mq, 0) RD_A(a[mq][1], buf, 1, mq, 1) }
        PHASE_SYNC()
        __builtin_amdgcn_s_setprio(1);
        MFMA_QUAD(1, 1)
        __builtin_amdgcn_s_setprio(0);
        __builtin_amdgcn_s_barrier();
#pragma unroll
        for (int nq = 0; nq < 2; ++nq) { RD_B(b[nq][0], buf, 0, nq, 0) RD_B(b[nq][1], buf, 0, nq, 1) }
        PHASE_SYNC()
        __builtin_amdgcn_s_setprio(1);
        MFMA_QUAD(1, 0)
        __builtin_amdgcn_s_setprio(0);
        asm volatile("s_waitcnt vmcnt(4)" ::: "memory");
        __builtin_amdgcn_s_barrier();
    }

    // ---- epilogue: coalesced fragment-major Cp read + add + tanh + store ----
    const unsigned short* cbase = Cp + (((size_t)(mt * 4 + ntile)) * 16) * 512 * 8;
    short8 cv[16];
#pragma unroll
    for (int ib = 0; ib < 16; ++ib)
        cv[ib] = *(const short8*)&cbase[((size_t)ib * 512 + tid) * 8];
#pragma unroll
    for (int m = 0; m < 8; ++m)
#pragma unroll
        for (int n = 0; n < 4; ++n) {
            int row = m0 + (m >> 2) * 128 + wr * 64 + (m & 3) * 16 + kg * 4;
            int col = n0 + (n >> 1) * 128 + wc * 32 + (n & 1) * 16 + r16;
            const int ib = m * 2 + (n >> 1);
#pragma unroll
            for (int r = 0; r < 4; ++r) {
                float cadd = bf2f((unsigned short)cv[ib][(n & 1) * 4 + r]);
                out[(size_t)(row + r) * HH + col] = fast_tanh(acc[m][n][r] + cadd);
            }
        }
}

extern "C" void kernel_launch(void* const* d_in, const int* in_sizes, int n_in,
                              void* d_out, int out_size, void* d_ws, size_t ws_size,
                              hipStream_t stream) {
    const float* enc  = (const float*)d_in[0];
    const float* ht   = (const float*)d_in[1];
    const int*   slen = (const int*)d_in[2];
    const float* pt   = (const float*)d_in[3];
    const float* Wa   = (const float*)d_in[4];
    const float* Wc   = (const float*)d_in[5];
    float* out = (float*)d_out;

    char* ws = (char*)d_ws;
    unsigned short* wehi = (unsigned short*)(ws + OFF_WEHI);
    unsigned short* welo = (unsigned short*)(ws + OFF_WELO);
    unsigned short* wahi = (unsigned short*)(ws + OFF_WAHI);
    unsigned short* walo = (unsigned short*)(ws + OFF_WALO);
    unsigned short* wcbf = (unsigned short*)(ws + OFF_WCBF);
    unsigned short* hbf  = (unsigned short*)(ws + OFF_HBF);
    unsigned short* uhi  = (unsigned short*)(ws + OFF_UHI);
    unsigned short* ulo  = (unsigned short*)(ws + OFF_ULO);
    unsigned short* ctxP = (unsigned short*)(ws + OFF_CTX);
    unsigned short* vt   = (unsigned short*)(ws + OFF_VT);

    hipFuncSetAttribute((const void*)k_out_gemm256,
                        hipFuncAttributeMaxDynamicSharedMemorySize, 131072);

    hipLaunchKernelGGL(k_prep, dim3(MU + 1024 + 2048 + 16384), dim3(256), 0, stream,
                       enc, ht, pt, slen, Wa, Wc, wehi, welo, wahi, walo, wcbf, hbf);
    hipLaunchKernelGGL(k_ugemm64, dim3(HH / 64, MU / 64), dim3(256), 0, stream,
                       wehi, welo, wahi, walo, uhi, ulo);
    hipLaunchKernelGGL(k_vgemm64, dim3(MU / 64, HH / 64), dim3(256), 0, stream,
                       wcbf, wehi, welo, vt);
    hipLaunchKernelGGL(k_attn2, dim3(NB * 8), dim3(256), 0, stream,
                       ht, uhi, ulo, vt, pt, slen, ctxP);
    hipLaunchKernelGGL(k_out_gemm256, dim3(256), dim3(512), 131072, stream,
                       hbf, wcbf, ctxP, out);
}